// Round 13
// baseline (319.582 us; speedup 1.0000x reference)
//
#include <hip/hip_runtime.h>

// NeuralHashVoxel round 13:
//  - bm01 ELIMINATED: occ0/occ1 vertex grids built by probing fidx directly,
//    fused into pre_k (same HBM bytes as the old stream, one less kernel, and
//    plain loads leave fidx01 LLC-warm for main's gathers)
//  - main kernel: 2 points/thread (chunked j, j+256) -> 2x MLP, shared gates
//  - rest identical to r12 (cell-validity grids all levels, Morton sort)

static constexpr int      NPTS  = 1048576;
static constexpr int      NF    = 8;
static constexpr int      TTAB  = 524288;
static constexpr unsigned BTAB  = 4194304u;          // 2^22 buckets per level
static constexpr unsigned BMASK = BTAB - 1u;
static constexpr unsigned P0 = 73856093u, P1 = 19349669u, P2 = 83492791u;

static constexpr int NBIN = 4096;        // 16^3 Morton bins, cell = 3.125
static constexpr int SB   = 256;
static constexpr int PPB  = NPTS / SB;
static constexpr int ITER = PPB / 256;
static constexpr int BCAP = 512;

// vertex-grid dims for levels 2..5 (scaled coords < 50,25,12.5,6.25)
static constexpr int S2 = 51, S3 = 26, S4 = 14, S5 = 8;
static constexpr int OCC2 = 0, OCC3 = OCC2 + S2*S2, OCC4 = OCC3 + S3*S3,
                     OCC5 = OCC4 + S4*S4, OCCW = OCC5 + S5*S5;
static constexpr int CB2 = 0, CB3 = CB2 + (S2-1)*(S2-1),
                     CB4 = CB3 + (S3-1)*(S3-1), CB5 = CB4 + (S4-1)*(S4-1),
                     CBW = CB5 + (S5-1)*(S5-1);                    // 3343
static constexpr int RB2 = (S2*S2+3)/4, RB3 = (S3*S3+3)/4,
                     RB4 = (S4*S4+3)/4, RB5 = (S5*S5+3)/4;
static constexpr int OCCB = RB2+RB3+RB4+RB5;                       // 885

// levels 0-1 dense grids
static constexpr int L0S = 201, L0C = 200, L0W = 4;
static constexpr int L1S = 101, L1C = 100, L1W = 2;
static constexpr int OCC0W_CNT = L0S * L0S * L0W;     // 161604 u64 (wave each)
static constexpr int OCC1W_CNT = L1S * L1S * L1W;     // 20402
static constexpr int CB0_CNT = L0C * L0C * L0W;       // 160000 u64
static constexpr int CB1_CNT = L1C * L1C * L1W;       // 20000
static constexpr int OCC01_WAVES = OCC0W_CNT + OCC1W_CNT;   // 182006
static constexpr int V01B = (OCC01_WAVES + 3) / 4;          // 45502 blocks
static constexpr int MIDC = CBW + CB0_CNT + CB1_CNT;        // 183343
static constexpr int MIDB = 16 + (MIDC + 255) / 256;

// d_out scratch layout (all consumed before main kernel writes out)
static constexpr size_t OUT_OCC25_OFF = 4u * 1024 * 1024;       // after hist
static constexpr size_t OUT_OCC0_OFF  = OUT_OCC25_OFF + 262144; // +256 KB pad
static constexpr size_t OUT_OCC1_OFF  = OUT_OCC0_OFF + 1572864; // +1.5 MB pad

// ws layout (read by main)
static constexpr size_t SORTED_BYTES = (size_t)NPTS * 16;   // 16 MB
static constexpr size_t CB25_OFF = SORTED_BYTES;
static constexpr size_t CB0_OFF  = CB25_OFF + 32768;
static constexpr size_t CB1_OFF  = CB0_OFF + 1310720;
static constexpr size_t BB_OFF   = CB1_OFF + 163840;
static constexpr size_t WS_FULL  = BB_OFF + (size_t)NBIN * 4;   // ~17.5 MB

typedef float f4 __attribute__((ext_vector_type(4)));

// ------------- per-point: all 6 levels gated by cell grids ------------------
__device__ __forceinline__ void nhv_point_g(
    float qx, float qy, float qz,
    const float* __restrict__ feat, const int* __restrict__ fidx,
    const unsigned long long* __restrict__ cbit25,
    const unsigned long long* __restrict__ cbit0,
    const unsigned long long* __restrict__ cbit1, float acc[NF])
{
    const int ix0 = (int)(qx * 4.0f), iy0 = (int)(qy * 4.0f), iz0 = (int)(qz * 4.0f);
    const int ix1 = (int)(qx * 2.0f), iy1 = (int)(qy * 2.0f), iz1 = (int)(qz * 2.0f);

    const unsigned long long w0 = cbit0[(size_t)(iz0 * L0C + iy0) * L0W + (ix0 >> 6)];
    const unsigned long long w1 = cbit1[(size_t)(iz1 * L1C + iy1) * L1W + (ix1 >> 6)];

    float fxh[4], fyh[4], fzh[4];
    int   ixh[4], iyh[4], izh[4];
    unsigned vm = 0;
    vm |= (unsigned)((w0 >> (ix0 & 63)) & 1ull) << 0;
    vm |= (unsigned)((w1 >> (ix1 & 63)) & 1ull) << 1;
    const int Ss[4]  = {S2, S3, S4, S5};
    const int CBo[4] = {CB2, CB3, CB4, CB5};
#pragma unroll
    for (int j = 0; j < 4; ++j) {
        const float inv = 1.0f / (float)(1 << j);      // 1, .5, .25, .125
        const float sx = qx*inv, sy = qy*inv, sz = qz*inv;
        const float bx = floorf(sx), by = floorf(sy), bz = floorf(sz);
        fxh[j] = sx-bx; fyh[j] = sy-by; fzh[j] = sz-bz;
        ixh[j] = (int)bx; iyh[j] = (int)by; izh[j] = (int)bz;
        const int C = Ss[j] - 1;
        const unsigned long long row = cbit25[CBo[j] + izh[j]*C + iyh[j]];
        vm |= (unsigned)((row >> ixh[j]) & 1ull) << (2 + j);
    }

#pragma unroll
    for (int f = 0; f < NF; ++f) acc[f] = 0.0f;

    // levels 0-1: gated gathers (gate == all 8 corner idx >= 0)
#pragma unroll
    for (int i = 0; i < 2; ++i) {
        if (vm & (1u << i)) {
            const float inv = (i == 0) ? 4.0f : 2.0f;  // exact pow2
            const float sx = qx*inv, sy = qy*inv, sz = qz*inv;
            const float bx = floorf(sx), by = floorf(sy), bz = floorf(sz);
            const unsigned h = (unsigned)(int)bx*P0 + (unsigned)(int)by*P1
                             + (unsigned)(int)bz*P2;
            const int* __restrict__ tab = fidx + (size_t)i * BTAB;
            int id[8];
#pragma unroll
            for (int k = 0; k < 8; ++k) {
                unsigned key = h;
                if (k & 4) key += P0;
                if (k & 2) key += P1;
                if (k & 1) key += P2;
                id[k] = tab[key & BMASK];
            }
            const float tx = sx - bx, ty = sy - by, tz = sz - bz;
            const float wxv[2] = {1.0f - tx, tx};
            const float wyv[2] = {1.0f - ty, ty};
            const float wzv[2] = {1.0f - tz, tz};
            const float* __restrict__ fb = feat + (size_t)i * (TTAB * NF);
#pragma unroll
            for (int k = 0; k < 8; ++k) {
                const float c = wxv[(k>>2)&1] * wyv[(k>>1)&1] * wzv[k&1];
                const float4* p = (const float4*)(fb + (size_t)id[k] * NF);
                const float4 lo = p[0], hi = p[1];
                acc[0]+=c*lo.x; acc[1]+=c*lo.y; acc[2]+=c*lo.z; acc[3]+=c*lo.w;
                acc[4]+=c*hi.x; acc[5]+=c*hi.y; acc[6]+=c*hi.z; acc[7]+=c*hi.w;
            }
        }
    }
    // levels 2-5
#pragma unroll
    for (int j = 0; j < 4; ++j) {
        if (vm & (1u << (2 + j))) {
            const int lvl = 2 + j;
            const unsigned h = (unsigned)ixh[j]*P0 + (unsigned)iyh[j]*P1
                             + (unsigned)izh[j]*P2;
            const int* __restrict__ tab = fidx + (size_t)lvl * BTAB;
            int id[8];
#pragma unroll
            for (int k = 0; k < 8; ++k) {
                unsigned key = h;
                if (k & 4) key += P0;
                if (k & 2) key += P1;
                if (k & 1) key += P2;
                id[k] = tab[key & BMASK];
            }
            const float wxv[2] = {1.0f - fxh[j], fxh[j]};
            const float wyv[2] = {1.0f - fyh[j], fyh[j]};
            const float wzv[2] = {1.0f - fzh[j], fzh[j]};
            const float* __restrict__ fb = feat + (size_t)lvl * (TTAB * NF);
#pragma unroll
            for (int k = 0; k < 8; ++k) {
                const float c = wxv[(k>>2)&1] * wyv[(k>>1)&1] * wzv[k&1];
                const float4* p = (const float4*)(fb + (size_t)id[k] * NF);
                const float4 lo = p[0], hi = p[1];
                acc[0]+=c*lo.x; acc[1]+=c*lo.y; acc[2]+=c*lo.z; acc[3]+=c*lo.w;
                acc[4]+=c*hi.x; acc[5]+=c*hi.y; acc[6]+=c*hi.z; acc[7]+=c*hi.w;
            }
        }
    }
}

// ---------------- plain per-point (ws-too-small fallback) -------------------
__device__ __forceinline__ void nhv_point(
    float qx, float qy, float qz,
    const float* __restrict__ feat, const int* __restrict__ fidx, float acc[NF])
{
    float fx[6], fy[6], fz[6];
    unsigned h[6];
#pragma unroll
    for (int i = 0; i < 6; ++i) {
        const float inv = 4.0f / (float)(1 << i);
        const float sx = qx*inv, sy = qy*inv, sz = qz*inv;
        const float bx = floorf(sx), by = floorf(sy), bz = floorf(sz);
        fx[i] = sx-bx; fy[i] = sy-by; fz[i] = sz-bz;
        h[i] = (unsigned)(int)bx*P0 + (unsigned)(int)by*P1 + (unsigned)(int)bz*P2;
    }
    int id[6][8];
#pragma unroll
    for (int i = 0; i < 6; ++i) {
        const int* __restrict__ tab = fidx + (size_t)i * BTAB;
#pragma unroll
        for (int k = 0; k < 8; ++k) {
            unsigned key = h[i];
            if (k & 4) key += P0;
            if (k & 2) key += P1;
            if (k & 1) key += P2;
            id[i][k] = tab[key & BMASK];
        }
    }
#pragma unroll
    for (int f = 0; f < NF; ++f) acc[f] = 0.0f;
#pragma unroll
    for (int i = 0; i < 6; ++i) {
        int mn = id[i][0];
#pragma unroll
        for (int k = 1; k < 8; ++k) mn = min(mn, id[i][k]);
        if (mn > -1) {
            const float wxv[2] = {1.0f - fx[i], fx[i]};
            const float wyv[2] = {1.0f - fy[i], fy[i]};
            const float wzv[2] = {1.0f - fz[i], fz[i]};
            const float* __restrict__ fb = feat + (size_t)i * (TTAB * NF);
#pragma unroll
            for (int k = 0; k < 8; ++k) {
                const float c = wxv[(k>>2)&1] * wyv[(k>>1)&1] * wzv[k&1];
                const float4* p = (const float4*)(fb + (size_t)id[i][k] * NF);
                const float4 lo = p[0], hi = p[1];
                acc[0]+=c*lo.x; acc[1]+=c*lo.y; acc[2]+=c*lo.z; acc[3]+=c*lo.w;
                acc[4]+=c*hi.x; acc[5]+=c*hi.y; acc[6]+=c*hi.z; acc[7]+=c*hi.w;
            }
        }
    }
}

// ---------------- binning ----------------
__device__ __forceinline__ unsigned expand4(unsigned v) {
    return (v & 1u) | ((v & 2u) << 2) | ((v & 4u) << 4) | ((v & 8u) << 6);
}
__device__ __forceinline__ unsigned bin_of(float x, float y, float z) {
    unsigned bx = min(15u, (unsigned)(int)(x * 0.32f));
    unsigned by = min(15u, (unsigned)(int)(y * 0.32f));
    unsigned bz = min(15u, (unsigned)(int)(z * 0.32f));
    return expand4(bx) | (expand4(by) << 1) | (expand4(bz) << 2);
}

// --- pre_k: occ2-5 || occ0/occ1 (direct fidx probes) || histogram -----------
__global__ __launch_bounds__(256) void pre_k(const int* __restrict__ fidx,
                                             unsigned long long* __restrict__ occ25,
                                             unsigned long long* __restrict__ occ0,
                                             unsigned long long* __restrict__ occ1,
                                             const float* __restrict__ qp,
                                             unsigned* __restrict__ hist) {
    __shared__ unsigned lh[NBIN];
    const int t = threadIdx.x, b = blockIdx.x;
    if (b < OCCB) {
        int lvl, S, occoff, bb = b;
        if (bb < RB2)              { lvl = 2; S = S2; occoff = OCC2; }
        else if ((bb -= RB2) < RB3){ lvl = 3; S = S3; occoff = OCC3; }
        else if ((bb -= RB3) < RB4){ lvl = 4; S = S4; occoff = OCC4; }
        else        { bb -= RB4;     lvl = 5; S = S5; occoff = OCC5; }
        const int row  = bb * 4 + (t >> 6);
        const int lane = t & 63;
        if (row < S * S) {
            const int y = row % S, z = row / S;
            bool v = false;
            if (lane < S) {
                const unsigned key = ((unsigned)lane*P0 + (unsigned)y*P1
                                    + (unsigned)z*P2) & BMASK;
                v = fidx[(size_t)lvl * BTAB + key] >= 0;
            }
            const unsigned long long m = __ballot(v);
            if (lane == 0) occ25[occoff + row] = m;
        }
    } else if (b < OCCB + V01B) {
        // direct vertex probes of fidx levels 0-1 (plain loads: warm the LLC)
        const int wid  = (b - OCCB) * 4 + (t >> 6);
        const int lane = t & 63;
        if (wid < OCC01_WAVES) {
            int S, row, wblk;
            const int* __restrict__ tab;
            unsigned long long* dst;
            if (wid < OCC0W_CNT) {
                S = L0S; row = wid >> 2; wblk = wid & 3;
                tab = fidx;        dst = occ0 + wid;
            } else {
                const int w1 = wid - OCC0W_CNT;
                S = L1S; row = w1 >> 1; wblk = w1 & 1;
                tab = fidx + BTAB; dst = occ1 + w1;
            }
            const int z = row / S, y = row % S;
            const int x = wblk * 64 + lane;
            bool v = false;
            if (x < S) {
                const unsigned key = ((unsigned)x*P0 + (unsigned)y*P1
                                    + (unsigned)z*P2) & BMASK;
                v = tab[key] >= 0;
            }
            const unsigned long long m = __ballot(v);
            if (lane == 0) *dst = m;
        }
    } else {
        const int bh = b - OCCB - V01B;
        for (int i = t; i < NBIN; i += 256) lh[i] = 0u;
        __syncthreads();
        const int base = bh * PPB;
#pragma unroll
        for (int i = 0; i < ITER; ++i) {
            const int p = base + i * 256 + t;
            const float x = __builtin_nontemporal_load(qp + 3*p);
            const float y = __builtin_nontemporal_load(qp + 3*p + 1);
            const float z = __builtin_nontemporal_load(qp + 3*p + 2);
            atomicAdd(&lh[bin_of(x, y, z)], 1u);
        }
        __syncthreads();
        for (int i = t; i < NBIN; i += 256)
            __builtin_nontemporal_store(lh[i], hist + (size_t)bh * NBIN + i);
    }
}

// ---- mid_k: colscan || cbit25 || cbit0 || cbit1 derivation -----------------
__global__ __launch_bounds__(256) void mid_k(unsigned* __restrict__ hist,
                                             unsigned* __restrict__ binbase,
                                             const unsigned long long* __restrict__ occ25,
                                             const unsigned long long* __restrict__ occ0,
                                             const unsigned long long* __restrict__ occ1,
                                             unsigned long long* __restrict__ cbit25,
                                             unsigned long long* __restrict__ cbit0,
                                             unsigned long long* __restrict__ cbit1) {
    const int t = threadIdx.x, b = blockIdx.x;
    if (b < 16) {
        const int bin = b * 256 + t;
        unsigned run = 0;
        for (int blk = 0; blk < SB; ++blk) {
            const unsigned v = hist[(size_t)blk * NBIN + bin];
            hist[(size_t)blk * NBIN + bin] = run;
            run += v;
        }
        binbase[bin] = run;
        return;
    }
    const int c = (b - 16) * 256 + t;
    if (c >= MIDC) return;
    if (c < CBW) {
        int S, occoff, cboff, local;
        if (c < CB3)      { S = S2; occoff = OCC2; cboff = CB2; local = c; }
        else if (c < CB4) { S = S3; occoff = OCC3; cboff = CB3; local = c - CB3; }
        else if (c < CB5) { S = S4; occoff = OCC4; cboff = CB4; local = c - CB4; }
        else              { S = S5; occoff = OCC5; cboff = CB5; local = c - CB5; }
        const int C = S - 1;
        const int cy = local % C, cz = local / C;
        const unsigned long long r00 = occ25[occoff +  cz      * S + cy    ];
        const unsigned long long r10 = occ25[occoff +  cz      * S + cy + 1];
        const unsigned long long r01 = occ25[occoff + (cz + 1) * S + cy    ];
        const unsigned long long r11 = occ25[occoff + (cz + 1) * S + cy + 1];
        cbit25[cboff + cz * C + cy] = (r00 & (r00 >> 1)) & (r10 & (r10 >> 1))
                                    & (r01 & (r01 >> 1)) & (r11 & (r11 >> 1));
    } else if (c < CBW + CB0_CNT) {
        const int c0 = c - CBW;
        const int w = c0 & 3, crow = c0 >> 2;
        const int cy = crow % L0C, cz = crow / L0C;
        unsigned long long res = ~0ull;
#pragma unroll
        for (int dy = 0; dy < 2; ++dy)
#pragma unroll
            for (int dz = 0; dz < 2; ++dz) {
                const unsigned long long* r =
                    occ0 + ((size_t)((cz + dz) * L0S + (cy + dy)) << 2);
                const unsigned long long a = r[w];
                const unsigned long long n = (w < 3) ? r[w + 1] : 0ull;
                res &= a & ((a >> 1) | (n << 63));
            }
        cbit0[c0] = res;
    } else {
        const int c1 = c - CBW - CB0_CNT;
        const int w = c1 & 1, crow = c1 >> 1;
        const int cy = crow % L1C, cz = crow / L1C;
        unsigned long long res = ~0ull;
#pragma unroll
        for (int dy = 0; dy < 2; ++dy)
#pragma unroll
            for (int dz = 0; dz < 2; ++dz) {
                const unsigned long long* r =
                    occ1 + ((size_t)((cz + dz) * L1S + (cy + dy)) << 1);
                const unsigned long long a = r[w];
                const unsigned long long n = (w < 1) ? r[w + 1] : 0ull;
                res &= a & ((a >> 1) | (n << 63));
            }
        cbit1[c1] = res;
    }
}

__global__ __launch_bounds__(256) void binscan_k(unsigned* __restrict__ binbase) {
    __shared__ unsigned tot[256];
    const int t = threadIdx.x;
    unsigned v[16];
    unsigned s = 0;
#pragma unroll
    for (int i = 0; i < 16; ++i) { v[i] = s; s += binbase[t * 16 + i]; }
    tot[t] = s;
    __syncthreads();
    for (int d = 1; d < 256; d <<= 1) {
        const unsigned x = (t >= d) ? tot[t - d] : 0u;
        __syncthreads();
        tot[t] += x;
        __syncthreads();
    }
    const unsigned cb = tot[t] - s;
#pragma unroll
    for (int i = 0; i < 16; ++i) binbase[t * 16 + i] = cb + v[i];
}

__global__ __launch_bounds__(256) void scatter_k(const float* __restrict__ qp,
                                                 const unsigned* __restrict__ hist,
                                                 const unsigned* __restrict__ binbase,
                                                 float4* __restrict__ sorted) {
    __shared__ unsigned cur[NBIN];
    const int b = blockIdx.x, t = threadIdx.x;
    for (int i = t; i < NBIN; i += 256)
        cur[i] = binbase[i] + hist[(size_t)b * NBIN + i];
    __syncthreads();
    const int base = b * PPB;
#pragma unroll
    for (int i = 0; i < ITER; ++i) {
        const int p = base + i * 256 + t;
        const float x = __builtin_nontemporal_load(qp + 3*p);
        const float y = __builtin_nontemporal_load(qp + 3*p + 1);
        const float z = __builtin_nontemporal_load(qp + 3*p + 2);
        const unsigned slot = atomicAdd(&cur[bin_of(x, y, z)], 1u);
        const f4 v = {x, y, z, __uint_as_float((unsigned)p)};
        __builtin_nontemporal_store(v, (f4*)sorted + slot);
    }
}

// ------- stage 2: per-bin 64-bucket counting sort (6-bit sub-Morton) --------
__global__ __launch_bounds__(256) void binsort_k(float4* __restrict__ sorted,
                                                 const unsigned* __restrict__ binbase) {
    __shared__ float4        pts[BCAP];
    __shared__ unsigned char sk[BCAP];
    __shared__ unsigned      cnt[64];
    const int bin = blockIdx.x, t = threadIdx.x;
    const unsigned start = binbase[bin];
    const unsigned end   = (bin < NBIN - 1) ? binbase[bin + 1] : (unsigned)NPTS;
    const int n = (int)(end - start);
    if (n <= 1 || n > BCAP) return;

    if (t < 64) cnt[t] = 0u;
    __syncthreads();
#pragma unroll
    for (int r = 0; r < BCAP / 256; ++r) {
        const int i = r * 256 + t;
        if (i < n) {
            const f4 pv = __builtin_nontemporal_load((const f4*)sorted + (start + i));
            const float4 p = make_float4(pv.x, pv.y, pv.z, pv.w);
            pts[i] = p;
            const unsigned ux = (unsigned)(int)(p.x * 1.28f) & 3u;
            const unsigned uy = (unsigned)(int)(p.y * 1.28f) & 3u;
            const unsigned uz = (unsigned)(int)(p.z * 1.28f) & 3u;
            const unsigned s = (ux & 1u) | ((uy & 1u) << 1) | ((uz & 1u) << 2)
                             | ((ux >> 1) << 3) | ((uy >> 1) << 4) | ((uz >> 1) << 5);
            sk[i] = (unsigned char)s;
            atomicAdd(&cnt[s], 1u);
        }
    }
    __syncthreads();
    if (t == 0) {
        unsigned run = 0;
#pragma unroll
        for (int i = 0; i < 64; ++i) { const unsigned v = cnt[i]; cnt[i] = run; run += v; }
    }
    __syncthreads();
#pragma unroll
    for (int r = 0; r < BCAP / 256; ++r) {
        const int i = r * 256 + t;
        if (i < n) {
            const unsigned dest = atomicAdd(&cnt[sk[i]], 1u);
            const float4 p = pts[i];
            const f4 v = {p.x, p.y, p.z, p.w};
            __builtin_nontemporal_store(v, (f4*)sorted + (start + dest));
        }
    }
}

// ------------- main kernel: 2 points/thread, XCD-slab swizzle ---------------
__global__ __launch_bounds__(256) void nhv_main_k(
    const float4* __restrict__ sp, const float* __restrict__ feat,
    const int* __restrict__ fidx,
    const unsigned long long* __restrict__ cbit25,
    const unsigned long long* __restrict__ cbit0,
    const unsigned long long* __restrict__ cbit1,
    float* __restrict__ out)
{
    const int nwg = NPTS / 512;                    // 2048 blocks
    const int bid = blockIdx.x;
    const int swz = (bid & 7) * (nwg >> 3) + (bid >> 3);
    const int j0  = swz * 512 + (int)threadIdx.x;  // chunk 0
    const int j1  = j0 + 256;                      // chunk 1 (adjacent Morton run)

    const f4 s0 = __builtin_nontemporal_load((const f4*)sp + j0);
    const f4 s1 = __builtin_nontemporal_load((const f4*)sp + j1);

    float a0[NF], a1[NF];
    nhv_point_g(s0.x, s0.y, s0.z, feat, fidx, cbit25, cbit0, cbit1, a0);
    nhv_point_g(s1.x, s1.y, s1.z, feat, fidx, cbit25, cbit0, cbit1, a1);

    const unsigned n0 = __float_as_uint(s0.w);
    const unsigned n1 = __float_as_uint(s1.w);
    f4* o0 = (f4*)(out + (size_t)n0 * NF);
    f4* o1 = (f4*)(out + (size_t)n1 * NF);
    f4 l0 = {a0[0], a0[1], a0[2], a0[3]};
    f4 h0 = {a0[4], a0[5], a0[6], a0[7]};
    f4 l1 = {a1[0], a1[1], a1[2], a1[3]};
    f4 h1 = {a1[4], a1[5], a1[6], a1[7]};
    __builtin_nontemporal_store(l0, o0);
    __builtin_nontemporal_store(h0, o0 + 1);
    __builtin_nontemporal_store(l1, o1);
    __builtin_nontemporal_store(h1, o1 + 1);
}

// ---------------- fallback ----------------
__global__ __launch_bounds__(256) void nhv_direct_k(
    const float* __restrict__ qp, const float* __restrict__ feat,
    const int* __restrict__ fidx, float* __restrict__ out)
{
    const int n = blockIdx.x * 256 + threadIdx.x;
    if (n >= NPTS) return;
    float acc[NF];
    nhv_point(qp[3*n], qp[3*n+1], qp[3*n+2], feat, fidx, acc);
    float4* o = (float4*)(out + (size_t)n * NF);
    o[0] = make_float4(acc[0], acc[1], acc[2], acc[3]);
    o[1] = make_float4(acc[4], acc[5], acc[6], acc[7]);
}

extern "C" void kernel_launch(void* const* d_in, const int* in_sizes, int n_in,
                              void* d_out, int out_size, void* d_ws, size_t ws_size,
                              hipStream_t stream) {
    const float* qp   = (const float*)d_in[0];
    const float* feat = (const float*)d_in[1];
    const int*   fidx = (const int*)d_in[2];
    float*       out  = (float*)d_out;

    if (ws_size >= WS_FULL) {
        // ws (read by main): sorted | cbit25 | cbit0 | cbit1 | binbase
        float4*             sorted  = (float4*)d_ws;
        unsigned long long* cbit25  = (unsigned long long*)((char*)d_ws + CB25_OFF);
        unsigned long long* cbit0   = (unsigned long long*)((char*)d_ws + CB0_OFF);
        unsigned long long* cbit1   = (unsigned long long*)((char*)d_ws + CB1_OFF);
        unsigned*           binbase = (unsigned*)((char*)d_ws + BB_OFF);
        // d_out scratch (all consumed before main overwrites out):
        unsigned*           hist  = (unsigned*)d_out;
        unsigned long long* occ25 = (unsigned long long*)((char*)d_out + OUT_OCC25_OFF);
        unsigned long long* occ0  = (unsigned long long*)((char*)d_out + OUT_OCC0_OFF);
        unsigned long long* occ1  = (unsigned long long*)((char*)d_out + OUT_OCC1_OFF);

        pre_k<<<dim3(OCCB + V01B + SB), dim3(256), 0, stream>>>(fidx, occ25, occ0, occ1, qp, hist);
        mid_k<<<dim3(MIDB), dim3(256), 0, stream>>>(hist, binbase, occ25, occ0, occ1,
                                                    cbit25, cbit0, cbit1);
        binscan_k<<<dim3(1), dim3(256), 0, stream>>>(binbase);
        scatter_k<<<dim3(SB), dim3(256), 0, stream>>>(qp, hist, binbase, sorted);
        binsort_k<<<dim3(NBIN), dim3(256), 0, stream>>>(sorted, binbase);
        nhv_main_k<<<dim3(NPTS/512), dim3(256), 0, stream>>>(sorted, feat, fidx,
                                                             cbit25, cbit0, cbit1, out);
    } else {
        nhv_direct_k<<<dim3(NPTS/256), dim3(256), 0, stream>>>(qp, feat, fidx, out);
    }
}

// Round 14
// 222.036 us; speedup vs baseline: 1.4393x; 1.4393x over previous
//
#include <hip/hip_runtime.h>

// NeuralHashVoxel round 14: r12 structure restored (best main: 110 us,
// FETCH 212 MB) with ONE fix: occ01_k restructured from 45K tiny blocks
// (1 dependent probe/thread) to 512 fat grid-stride blocks, 4 words per
// wave-iteration (4x MLP on the L2-resident bm01 probes).
// r13 lessons: bm01 is the essential compression step (direct fidx probes =
// 533 MB random fetch); 2pt/thread main is worse than 1pt (VGPR/divergence).

static constexpr int      NPTS  = 1048576;
static constexpr int      NF    = 8;
static constexpr int      TTAB  = 524288;
static constexpr unsigned BTAB  = 4194304u;          // 2^22 buckets per level
static constexpr unsigned BMASK = BTAB - 1u;
static constexpr unsigned P0 = 73856093u, P1 = 19349669u, P2 = 83492791u;

static constexpr int NBIN = 4096;        // 16^3 Morton bins, cell = 3.125
static constexpr int SB   = 256;
static constexpr int PPB  = NPTS / SB;
static constexpr int ITER = PPB / 256;
static constexpr int BCAP = 512;

// vertex-grid dims for levels 2..5 (scaled coords < 50,25,12.5,6.25)
static constexpr int S2 = 51, S3 = 26, S4 = 14, S5 = 8;
static constexpr int OCC2 = 0, OCC3 = OCC2 + S2*S2, OCC4 = OCC3 + S3*S3,
                     OCC5 = OCC4 + S4*S4, OCCW = OCC5 + S5*S5;
static constexpr int CB2 = 0, CB3 = CB2 + (S2-1)*(S2-1),
                     CB4 = CB3 + (S3-1)*(S3-1), CB5 = CB4 + (S4-1)*(S4-1),
                     CBW = CB5 + (S5-1)*(S5-1);                    // 3343
static constexpr int RB2 = (S2*S2+3)/4, RB3 = (S3*S3+3)/4,
                     RB4 = (S4*S4+3)/4, RB5 = (S5*S5+3)/4;
static constexpr int OCCB = RB2+RB3+RB4+RB5;                       // 885

// levels 0-1 dense grids
static constexpr int L0S = 201, L0C = 200, L0W = 4;
static constexpr int L1S = 101, L1C = 100, L1W = 2;
static constexpr int OCC0W_CNT = L0S * L0S * L0W;     // 161604 u64 words
static constexpr int OCC1W_CNT = L1S * L1S * L1W;     // 20402
static constexpr int CB0_CNT = L0C * L0C * L0W;       // 160000 u64
static constexpr int CB1_CNT = L1C * L1C * L1W;       // 20000
static constexpr int OCC01_WORDS = OCC0W_CNT + OCC1W_CNT;   // 182006
static constexpr int MIDC = CBW + CB0_CNT + CB1_CNT;        // 183343
static constexpr int MIDB = 16 + (MIDC + 255) / 256;

// bm01: wave-ballot layout. bucket B (lvl*BTAB+key):
//   u64 word = ((B>>8)<<2) | (B&3), bit = (B>>2)&63
static constexpr int BM01_WAVES = (int)(2 * BTAB / 256);    // 32768
static constexpr int BM01B = BM01_WAVES / 4;                // 8192 blocks

// d_out scratch layout (all consumed before main kernel writes out)
static constexpr size_t OUT_BM01_OFF  = 4u  * 1024 * 1024;  // 1 MB
static constexpr size_t OUT_OCC25_OFF = 5u  * 1024 * 1024;  // ~28 KB
static constexpr size_t OUT_OCC0_OFF  = 5632u * 1024;       // 1.3 MB
static constexpr size_t OUT_OCC1_OFF  = 7u  * 1024 * 1024;  // ~160 KB

// ws layout (read by main)
static constexpr size_t SORTED_BYTES = (size_t)NPTS * 16;   // 16 MB
static constexpr size_t CB25_OFF = SORTED_BYTES;
static constexpr size_t CB0_OFF  = CB25_OFF + 32768;
static constexpr size_t CB1_OFF  = CB0_OFF + 1310720;
static constexpr size_t BB_OFF   = CB1_OFF + 163840;
static constexpr size_t WS_FULL  = BB_OFF + (size_t)NBIN * 4;   // ~17.5 MB

typedef float f4 __attribute__((ext_vector_type(4)));
typedef int   i4 __attribute__((ext_vector_type(4)));

// ------------- per-point: all 6 levels gated by cell grids ------------------
__device__ __forceinline__ void nhv_point_g(
    float qx, float qy, float qz,
    const float* __restrict__ feat, const int* __restrict__ fidx,
    const unsigned long long* __restrict__ cbit25,
    const unsigned long long* __restrict__ cbit0,
    const unsigned long long* __restrict__ cbit1, float acc[NF])
{
    const int ix0 = (int)(qx * 4.0f), iy0 = (int)(qy * 4.0f), iz0 = (int)(qz * 4.0f);
    const int ix1 = (int)(qx * 2.0f), iy1 = (int)(qy * 2.0f), iz1 = (int)(qz * 2.0f);

    const unsigned long long w0 = cbit0[(size_t)(iz0 * L0C + iy0) * L0W + (ix0 >> 6)];
    const unsigned long long w1 = cbit1[(size_t)(iz1 * L1C + iy1) * L1W + (ix1 >> 6)];

    float fxh[4], fyh[4], fzh[4];
    int   ixh[4], iyh[4], izh[4];
    unsigned vm = 0;
    vm |= (unsigned)((w0 >> (ix0 & 63)) & 1ull) << 0;
    vm |= (unsigned)((w1 >> (ix1 & 63)) & 1ull) << 1;
    const int Ss[4]  = {S2, S3, S4, S5};
    const int CBo[4] = {CB2, CB3, CB4, CB5};
#pragma unroll
    for (int j = 0; j < 4; ++j) {
        const float inv = 1.0f / (float)(1 << j);      // 1, .5, .25, .125
        const float sx = qx*inv, sy = qy*inv, sz = qz*inv;
        const float bx = floorf(sx), by = floorf(sy), bz = floorf(sz);
        fxh[j] = sx-bx; fyh[j] = sy-by; fzh[j] = sz-bz;
        ixh[j] = (int)bx; iyh[j] = (int)by; izh[j] = (int)bz;
        const int C = Ss[j] - 1;
        const unsigned long long row = cbit25[CBo[j] + izh[j]*C + iyh[j]];
        vm |= (unsigned)((row >> ixh[j]) & 1ull) << (2 + j);
    }

#pragma unroll
    for (int f = 0; f < NF; ++f) acc[f] = 0.0f;

    // levels 0-1: gated gathers (gate == all 8 corner idx >= 0)
#pragma unroll
    for (int i = 0; i < 2; ++i) {
        if (vm & (1u << i)) {
            const float inv = (i == 0) ? 4.0f : 2.0f;  // exact pow2
            const float sx = qx*inv, sy = qy*inv, sz = qz*inv;
            const float bx = floorf(sx), by = floorf(sy), bz = floorf(sz);
            const unsigned h = (unsigned)(int)bx*P0 + (unsigned)(int)by*P1
                             + (unsigned)(int)bz*P2;
            const int* __restrict__ tab = fidx + (size_t)i * BTAB;
            int id[8];
#pragma unroll
            for (int k = 0; k < 8; ++k) {
                unsigned key = h;
                if (k & 4) key += P0;
                if (k & 2) key += P1;
                if (k & 1) key += P2;
                id[k] = tab[key & BMASK];
            }
            const float tx = sx - bx, ty = sy - by, tz = sz - bz;
            const float wxv[2] = {1.0f - tx, tx};
            const float wyv[2] = {1.0f - ty, ty};
            const float wzv[2] = {1.0f - tz, tz};
            const float* __restrict__ fb = feat + (size_t)i * (TTAB * NF);
#pragma unroll
            for (int k = 0; k < 8; ++k) {
                const float c = wxv[(k>>2)&1] * wyv[(k>>1)&1] * wzv[k&1];
                const float4* p = (const float4*)(fb + (size_t)id[k] * NF);
                const float4 lo = p[0], hi = p[1];
                acc[0]+=c*lo.x; acc[1]+=c*lo.y; acc[2]+=c*lo.z; acc[3]+=c*lo.w;
                acc[4]+=c*hi.x; acc[5]+=c*hi.y; acc[6]+=c*hi.z; acc[7]+=c*hi.w;
            }
        }
    }
    // levels 2-5
#pragma unroll
    for (int j = 0; j < 4; ++j) {
        if (vm & (1u << (2 + j))) {
            const int lvl = 2 + j;
            const unsigned h = (unsigned)ixh[j]*P0 + (unsigned)iyh[j]*P1
                             + (unsigned)izh[j]*P2;
            const int* __restrict__ tab = fidx + (size_t)lvl * BTAB;
            int id[8];
#pragma unroll
            for (int k = 0; k < 8; ++k) {
                unsigned key = h;
                if (k & 4) key += P0;
                if (k & 2) key += P1;
                if (k & 1) key += P2;
                id[k] = tab[key & BMASK];
            }
            const float wxv[2] = {1.0f - fxh[j], fxh[j]};
            const float wyv[2] = {1.0f - fyh[j], fyh[j]};
            const float wzv[2] = {1.0f - fzh[j], fzh[j]};
            const float* __restrict__ fb = feat + (size_t)lvl * (TTAB * NF);
#pragma unroll
            for (int k = 0; k < 8; ++k) {
                const float c = wxv[(k>>2)&1] * wyv[(k>>1)&1] * wzv[k&1];
                const float4* p = (const float4*)(fb + (size_t)id[k] * NF);
                const float4 lo = p[0], hi = p[1];
                acc[0]+=c*lo.x; acc[1]+=c*lo.y; acc[2]+=c*lo.z; acc[3]+=c*lo.w;
                acc[4]+=c*hi.x; acc[5]+=c*hi.y; acc[6]+=c*hi.z; acc[7]+=c*hi.w;
            }
        }
    }
}

// ---------------- plain per-point (ws-too-small fallback) -------------------
__device__ __forceinline__ void nhv_point(
    float qx, float qy, float qz,
    const float* __restrict__ feat, const int* __restrict__ fidx, float acc[NF])
{
    float fx[6], fy[6], fz[6];
    unsigned h[6];
#pragma unroll
    for (int i = 0; i < 6; ++i) {
        const float inv = 4.0f / (float)(1 << i);
        const float sx = qx*inv, sy = qy*inv, sz = qz*inv;
        const float bx = floorf(sx), by = floorf(sy), bz = floorf(sz);
        fx[i] = sx-bx; fy[i] = sy-by; fz[i] = sz-bz;
        h[i] = (unsigned)(int)bx*P0 + (unsigned)(int)by*P1 + (unsigned)(int)bz*P2;
    }
    int id[6][8];
#pragma unroll
    for (int i = 0; i < 6; ++i) {
        const int* __restrict__ tab = fidx + (size_t)i * BTAB;
#pragma unroll
        for (int k = 0; k < 8; ++k) {
            unsigned key = h[i];
            if (k & 4) key += P0;
            if (k & 2) key += P1;
            if (k & 1) key += P2;
            id[i][k] = tab[key & BMASK];
        }
    }
#pragma unroll
    for (int f = 0; f < NF; ++f) acc[f] = 0.0f;
#pragma unroll
    for (int i = 0; i < 6; ++i) {
        int mn = id[i][0];
#pragma unroll
        for (int k = 1; k < 8; ++k) mn = min(mn, id[i][k]);
        if (mn > -1) {
            const float wxv[2] = {1.0f - fx[i], fx[i]};
            const float wyv[2] = {1.0f - fy[i], fy[i]};
            const float wzv[2] = {1.0f - fz[i], fz[i]};
            const float* __restrict__ fb = feat + (size_t)i * (TTAB * NF);
#pragma unroll
            for (int k = 0; k < 8; ++k) {
                const float c = wxv[(k>>2)&1] * wyv[(k>>1)&1] * wzv[k&1];
                const float4* p = (const float4*)(fb + (size_t)id[i][k] * NF);
                const float4 lo = p[0], hi = p[1];
                acc[0]+=c*lo.x; acc[1]+=c*lo.y; acc[2]+=c*lo.z; acc[3]+=c*lo.w;
                acc[4]+=c*hi.x; acc[5]+=c*hi.y; acc[6]+=c*hi.z; acc[7]+=c*hi.w;
            }
        }
    }
}

// ---------------- binning ----------------
__device__ __forceinline__ unsigned expand4(unsigned v) {
    return (v & 1u) | ((v & 2u) << 2) | ((v & 4u) << 4) | ((v & 8u) << 6);
}
__device__ __forceinline__ unsigned bin_of(float x, float y, float z) {
    unsigned bx = min(15u, (unsigned)(int)(x * 0.32f));
    unsigned by = min(15u, (unsigned)(int)(y * 0.32f));
    unsigned bz = min(15u, (unsigned)(int)(z * 0.32f));
    return expand4(bx) | (expand4(by) << 1) | (expand4(bz) << 2);
}

// --- pre_k: occ2-5 grids || bm01 build (coalesced ballot) || histogram ------
__global__ __launch_bounds__(256) void pre_k(const int* __restrict__ fidx,
                                             unsigned long long* __restrict__ occ25,
                                             unsigned long long* __restrict__ bm01,
                                             const float* __restrict__ qp,
                                             unsigned* __restrict__ hist) {
    __shared__ unsigned lh[NBIN];
    const int t = threadIdx.x, b = blockIdx.x;
    if (b < OCCB) {
        int lvl, S, occoff, bb = b;
        if (bb < RB2)              { lvl = 2; S = S2; occoff = OCC2; }
        else if ((bb -= RB2) < RB3){ lvl = 3; S = S3; occoff = OCC3; }
        else if ((bb -= RB3) < RB4){ lvl = 4; S = S4; occoff = OCC4; }
        else        { bb -= RB4;     lvl = 5; S = S5; occoff = OCC5; }
        const int row  = bb * 4 + (t >> 6);
        const int lane = t & 63;
        if (row < S * S) {
            const int y = row % S, z = row / S;
            bool v = false;
            if (lane < S) {
                const unsigned key = ((unsigned)lane*P0 + (unsigned)y*P1
                                    + (unsigned)z*P2) & BMASK;
                v = fidx[(size_t)lvl * BTAB + key] >= 0;
            }
            const unsigned long long m = __ballot(v);
            if (lane == 0) occ25[occoff + row] = m;
        }
    } else if (b < OCCB + BM01B) {
        // bm01: wave w covers buckets [w*256,(w+1)*256); lane l: buckets 4l+k
        const int tid  = (b - OCCB) * 256 + t;
        const int w    = tid >> 6;
        const int lane = tid & 63;
        const i4 v = __builtin_nontemporal_load(
                        (const i4*)(fidx + (size_t)w * 256) + lane);
        const unsigned long long m0 = __ballot(v.x >= 0);
        const unsigned long long m1 = __ballot(v.y >= 0);
        const unsigned long long m2 = __ballot(v.z >= 0);
        const unsigned long long m3 = __ballot(v.w >= 0);
        if (lane == 0) {
            unsigned long long* d = bm01 + ((size_t)w << 2);
            d[0] = m0; d[1] = m1; d[2] = m2; d[3] = m3;
        }
    } else {
        const int bh = b - OCCB - BM01B;
        for (int i = t; i < NBIN; i += 256) lh[i] = 0u;
        __syncthreads();
        const int base = bh * PPB;
#pragma unroll
        for (int i = 0; i < ITER; ++i) {
            const int p = base + i * 256 + t;
            const float x = __builtin_nontemporal_load(qp + 3*p);
            const float y = __builtin_nontemporal_load(qp + 3*p + 1);
            const float z = __builtin_nontemporal_load(qp + 3*p + 2);
            atomicAdd(&lh[bin_of(x, y, z)], 1u);
        }
        __syncthreads();
        for (int i = t; i < NBIN; i += 256)
            __builtin_nontemporal_store(lh[i], hist + (size_t)bh * NBIN + i);
    }
}

// --- occ01_k: vertex grids lvl0/1 from L2-resident bm01 ---------------------
//  512 fat blocks, grid-stride; each wave does 4 words/iter (4x MLP).
__global__ __launch_bounds__(256) void occ01_k(
    const unsigned long long* __restrict__ bm01,
    unsigned long long* __restrict__ occ0,
    unsigned long long* __restrict__ occ1)
{
    const int lane   = threadIdx.x & 63;
    const int wid    = (blockIdx.x * 256 + threadIdx.x) >> 6;   // global wave id
    const int nwaves = (int)gridDim.x * 4;
    const int ngroups = (OCC01_WORDS + 3) / 4;

    for (int g = wid; g < ngroups; g += nwaves) {
        unsigned long long vals[4];
        bool ok[4];
#pragma unroll
        for (int k = 0; k < 4; ++k) {
            const int w = g * 4 + k;
            ok[k] = (w < OCC01_WORDS);
            bool v = false;
            if (ok[k]) {
                int S, row, wblk, lvl;
                if (w < OCC0W_CNT) { lvl = 0; S = L0S; row = w >> 2; wblk = w & 3; }
                else { lvl = 1; S = L1S; const int w1 = w - OCC0W_CNT; row = w1 >> 1; wblk = w1 & 1; }
                const int z = row / S, y = row % S;
                const int x = wblk * 64 + lane;
                if (x < S) {
                    const unsigned key = ((unsigned)x*P0 + (unsigned)y*P1
                                        + (unsigned)z*P2) & BMASK;
                    const unsigned B = (unsigned)lvl * BTAB + key;
                    const unsigned long long word =
                        bm01[((size_t)(B >> 8) << 2) | (B & 3u)];
                    v = (word >> ((B >> 2) & 63u)) & 1ull;
                }
            }
            vals[k] = v ? 1ull : 0ull;   // placeholder; ballot next
        }
#pragma unroll
        for (int k = 0; k < 4; ++k) {
            const unsigned long long m = __ballot(vals[k] != 0ull);
            const int w = g * 4 + k;
            if (ok[k] && lane == 0) {
                if (w < OCC0W_CNT) occ0[w] = m;
                else               occ1[w - OCC0W_CNT] = m;
            }
        }
    }
}

// ---- mid_k: colscan || cbit25 || cbit0 || cbit1 derivation -----------------
__global__ __launch_bounds__(256) void mid_k(unsigned* __restrict__ hist,
                                             unsigned* __restrict__ binbase,
                                             const unsigned long long* __restrict__ occ25,
                                             const unsigned long long* __restrict__ occ0,
                                             const unsigned long long* __restrict__ occ1,
                                             unsigned long long* __restrict__ cbit25,
                                             unsigned long long* __restrict__ cbit0,
                                             unsigned long long* __restrict__ cbit1) {
    const int t = threadIdx.x, b = blockIdx.x;
    if (b < 16) {
        const int bin = b * 256 + t;
        unsigned run = 0;
        for (int blk = 0; blk < SB; ++blk) {
            const unsigned v = hist[(size_t)blk * NBIN + bin];
            hist[(size_t)blk * NBIN + bin] = run;
            run += v;
        }
        binbase[bin] = run;
        return;
    }
    const int c = (b - 16) * 256 + t;
    if (c >= MIDC) return;
    if (c < CBW) {
        int S, occoff, cboff, local;
        if (c < CB3)      { S = S2; occoff = OCC2; cboff = CB2; local = c; }
        else if (c < CB4) { S = S3; occoff = OCC3; cboff = CB3; local = c - CB3; }
        else if (c < CB5) { S = S4; occoff = OCC4; cboff = CB4; local = c - CB4; }
        else              { S = S5; occoff = OCC5; cboff = CB5; local = c - CB5; }
        const int C = S - 1;
        const int cy = local % C, cz = local / C;
        const unsigned long long r00 = occ25[occoff +  cz      * S + cy    ];
        const unsigned long long r10 = occ25[occoff +  cz      * S + cy + 1];
        const unsigned long long r01 = occ25[occoff + (cz + 1) * S + cy    ];
        const unsigned long long r11 = occ25[occoff + (cz + 1) * S + cy + 1];
        cbit25[cboff + cz * C + cy] = (r00 & (r00 >> 1)) & (r10 & (r10 >> 1))
                                    & (r01 & (r01 >> 1)) & (r11 & (r11 >> 1));
    } else if (c < CBW + CB0_CNT) {
        const int c0 = c - CBW;
        const int w = c0 & 3, crow = c0 >> 2;
        const int cy = crow % L0C, cz = crow / L0C;
        unsigned long long res = ~0ull;
#pragma unroll
        for (int dy = 0; dy < 2; ++dy)
#pragma unroll
            for (int dz = 0; dz < 2; ++dz) {
                const unsigned long long* r =
                    occ0 + ((size_t)((cz + dz) * L0S + (cy + dy)) << 2);
                const unsigned long long a = r[w];
                const unsigned long long n = (w < 3) ? r[w + 1] : 0ull;
                res &= a & ((a >> 1) | (n << 63));
            }
        cbit0[c0] = res;
    } else {
        const int c1 = c - CBW - CB0_CNT;
        const int w = c1 & 1, crow = c1 >> 1;
        const int cy = crow % L1C, cz = crow / L1C;
        unsigned long long res = ~0ull;
#pragma unroll
        for (int dy = 0; dy < 2; ++dy)
#pragma unroll
            for (int dz = 0; dz < 2; ++dz) {
                const unsigned long long* r =
                    occ1 + ((size_t)((cz + dz) * L1S + (cy + dy)) << 1);
                const unsigned long long a = r[w];
                const unsigned long long n = (w < 1) ? r[w + 1] : 0ull;
                res &= a & ((a >> 1) | (n << 63));
            }
        cbit1[c1] = res;
    }
}

__global__ __launch_bounds__(256) void binscan_k(unsigned* __restrict__ binbase) {
    __shared__ unsigned tot[256];
    const int t = threadIdx.x;
    unsigned v[16];
    unsigned s = 0;
#pragma unroll
    for (int i = 0; i < 16; ++i) { v[i] = s; s += binbase[t * 16 + i]; }
    tot[t] = s;
    __syncthreads();
    for (int d = 1; d < 256; d <<= 1) {
        const unsigned x = (t >= d) ? tot[t - d] : 0u;
        __syncthreads();
        tot[t] += x;
        __syncthreads();
    }
    const unsigned cb = tot[t] - s;
#pragma unroll
    for (int i = 0; i < 16; ++i) binbase[t * 16 + i] = cb + v[i];
}

__global__ __launch_bounds__(256) void scatter_k(const float* __restrict__ qp,
                                                 const unsigned* __restrict__ hist,
                                                 const unsigned* __restrict__ binbase,
                                                 float4* __restrict__ sorted) {
    __shared__ unsigned cur[NBIN];
    const int b = blockIdx.x, t = threadIdx.x;
    for (int i = t; i < NBIN; i += 256)
        cur[i] = binbase[i] + hist[(size_t)b * NBIN + i];
    __syncthreads();
    const int base = b * PPB;
#pragma unroll
    for (int i = 0; i < ITER; ++i) {
        const int p = base + i * 256 + t;
        const float x = __builtin_nontemporal_load(qp + 3*p);
        const float y = __builtin_nontemporal_load(qp + 3*p + 1);
        const float z = __builtin_nontemporal_load(qp + 3*p + 2);
        const unsigned slot = atomicAdd(&cur[bin_of(x, y, z)], 1u);
        const f4 v = {x, y, z, __uint_as_float((unsigned)p)};
        __builtin_nontemporal_store(v, (f4*)sorted + slot);
    }
}

// ------- stage 2: per-bin 64-bucket counting sort (6-bit sub-Morton) --------
__global__ __launch_bounds__(256) void binsort_k(float4* __restrict__ sorted,
                                                 const unsigned* __restrict__ binbase) {
    __shared__ float4        pts[BCAP];
    __shared__ unsigned char sk[BCAP];
    __shared__ unsigned      cnt[64];
    const int bin = blockIdx.x, t = threadIdx.x;
    const unsigned start = binbase[bin];
    const unsigned end   = (bin < NBIN - 1) ? binbase[bin + 1] : (unsigned)NPTS;
    const int n = (int)(end - start);
    if (n <= 1 || n > BCAP) return;

    if (t < 64) cnt[t] = 0u;
    __syncthreads();
#pragma unroll
    for (int r = 0; r < BCAP / 256; ++r) {
        const int i = r * 256 + t;
        if (i < n) {
            const f4 pv = __builtin_nontemporal_load((const f4*)sorted + (start + i));
            const float4 p = make_float4(pv.x, pv.y, pv.z, pv.w);
            pts[i] = p;
            const unsigned ux = (unsigned)(int)(p.x * 1.28f) & 3u;
            const unsigned uy = (unsigned)(int)(p.y * 1.28f) & 3u;
            const unsigned uz = (unsigned)(int)(p.z * 1.28f) & 3u;
            const unsigned s = (ux & 1u) | ((uy & 1u) << 1) | ((uz & 1u) << 2)
                             | ((ux >> 1) << 3) | ((uy >> 1) << 4) | ((uz >> 1) << 5);
            sk[i] = (unsigned char)s;
            atomicAdd(&cnt[s], 1u);
        }
    }
    __syncthreads();
    if (t == 0) {
        unsigned run = 0;
#pragma unroll
        for (int i = 0; i < 64; ++i) { const unsigned v = cnt[i]; cnt[i] = run; run += v; }
    }
    __syncthreads();
#pragma unroll
    for (int r = 0; r < BCAP / 256; ++r) {
        const int i = r * 256 + t;
        if (i < n) {
            const unsigned dest = atomicAdd(&cnt[sk[i]], 1u);
            const float4 p = pts[i];
            const f4 v = {p.x, p.y, p.z, p.w};
            __builtin_nontemporal_store(v, (f4*)sorted + (start + dest));
        }
    }
}

// ---------------- main kernel (1 pt/thread, XCD-slab swizzle) ---------------
__global__ __launch_bounds__(256) void nhv_main_k(
    const float4* __restrict__ sp, const float* __restrict__ feat,
    const int* __restrict__ fidx,
    const unsigned long long* __restrict__ cbit25,
    const unsigned long long* __restrict__ cbit0,
    const unsigned long long* __restrict__ cbit1,
    float* __restrict__ out)
{
    const int nwg = NPTS / 256;
    const int bid = blockIdx.x;
    const int swz = (bid & 7) * (nwg >> 3) + (bid >> 3);
    const int j   = swz * 256 + (int)threadIdx.x;

    const f4 s = __builtin_nontemporal_load((const f4*)sp + j);
    float acc[NF];
    nhv_point_g(s.x, s.y, s.z, feat, fidx, cbit25, cbit0, cbit1, acc);
    const unsigned n = __float_as_uint(s.w);
    f4* o = (f4*)(out + (size_t)n * NF);
    f4 lo = {acc[0], acc[1], acc[2], acc[3]};
    f4 hi = {acc[4], acc[5], acc[6], acc[7]};
    __builtin_nontemporal_store(lo, o);
    __builtin_nontemporal_store(hi, o + 1);
}

// ---------------- fallback ----------------
__global__ __launch_bounds__(256) void nhv_direct_k(
    const float* __restrict__ qp, const float* __restrict__ feat,
    const int* __restrict__ fidx, float* __restrict__ out)
{
    const int n = blockIdx.x * 256 + threadIdx.x;
    if (n >= NPTS) return;
    float acc[NF];
    nhv_point(qp[3*n], qp[3*n+1], qp[3*n+2], feat, fidx, acc);
    float4* o = (float4*)(out + (size_t)n * NF);
    o[0] = make_float4(acc[0], acc[1], acc[2], acc[3]);
    o[1] = make_float4(acc[4], acc[5], acc[6], acc[7]);
}

extern "C" void kernel_launch(void* const* d_in, const int* in_sizes, int n_in,
                              void* d_out, int out_size, void* d_ws, size_t ws_size,
                              hipStream_t stream) {
    const float* qp   = (const float*)d_in[0];
    const float* feat = (const float*)d_in[1];
    const int*   fidx = (const int*)d_in[2];
    float*       out  = (float*)d_out;

    if (ws_size >= WS_FULL) {
        // ws (read by main): sorted | cbit25 | cbit0 | cbit1 | binbase
        float4*             sorted  = (float4*)d_ws;
        unsigned long long* cbit25  = (unsigned long long*)((char*)d_ws + CB25_OFF);
        unsigned long long* cbit0   = (unsigned long long*)((char*)d_ws + CB0_OFF);
        unsigned long long* cbit1   = (unsigned long long*)((char*)d_ws + CB1_OFF);
        unsigned*           binbase = (unsigned*)((char*)d_ws + BB_OFF);
        // d_out scratch (all consumed before main overwrites out):
        unsigned*           hist  = (unsigned*)d_out;
        unsigned long long* bm01  = (unsigned long long*)((char*)d_out + OUT_BM01_OFF);
        unsigned long long* occ25 = (unsigned long long*)((char*)d_out + OUT_OCC25_OFF);
        unsigned long long* occ0  = (unsigned long long*)((char*)d_out + OUT_OCC0_OFF);
        unsigned long long* occ1  = (unsigned long long*)((char*)d_out + OUT_OCC1_OFF);

        pre_k<<<dim3(OCCB + BM01B + SB), dim3(256), 0, stream>>>(fidx, occ25, bm01, qp, hist);
        occ01_k<<<dim3(512), dim3(256), 0, stream>>>(bm01, occ0, occ1);
        mid_k<<<dim3(MIDB), dim3(256), 0, stream>>>(hist, binbase, occ25, occ0, occ1,
                                                    cbit25, cbit0, cbit1);
        binscan_k<<<dim3(1), dim3(256), 0, stream>>>(binbase);
        scatter_k<<<dim3(SB), dim3(256), 0, stream>>>(qp, hist, binbase, sorted);
        binsort_k<<<dim3(NBIN), dim3(256), 0, stream>>>(sorted, binbase);
        nhv_main_k<<<dim3(NPTS/256), dim3(256), 0, stream>>>(sorted, feat, fidx,
                                                             cbit25, cbit0, cbit1, out);
    } else {
        nhv_direct_k<<<dim3(NPTS/256), dim3(256), 0, stream>>>(qp, feat, fidx, out);
    }
}

// Round 15
// 206.951 us; speedup vs baseline: 1.5442x; 1.0729x over previous
//
#include <hip/hip_runtime.h>

// NeuralHashVoxel round 15: pipeline consolidation.
//  - 5 launches: pre_k -> os_k (colscan||occ01) -> cb_k (binscan||derives)
//    -> scatter_k -> main_k (binsort FUSED, no launch-bounds cap)
//  - coarse gates packed: b2[50^3] bytes (lvl2), b345[25^3] bytes (lvl3/4/5
//    bits; cells are shifts of lvl3 cell) -> 4 gate loads/point instead of 6
//  - integer cells from shifts of ix0 (exact for pow2 scales, coords >= 0)

static constexpr int      NPTS  = 1048576;
static constexpr int      NF    = 8;
static constexpr int      TTAB  = 524288;
static constexpr unsigned BTAB  = 4194304u;          // 2^22 buckets per level
static constexpr unsigned BMASK = BTAB - 1u;
static constexpr unsigned P0 = 73856093u, P1 = 19349669u, P2 = 83492791u;

static constexpr int NBIN = 4096;        // 16^3 Morton bins, cell = 3.125
static constexpr int SB   = 256;
static constexpr int PPB  = NPTS / SB;
static constexpr int ITER = PPB / 256;
static constexpr int BCAP = 512;

// vertex-grid dims for levels 2..5 (scaled coords < 50,25,12.5,6.25)
static constexpr int S2 = 51, S3 = 26, S4 = 14, S5 = 8;
static constexpr int OCC2 = 0, OCC3 = OCC2 + S2*S2, OCC4 = OCC3 + S3*S3,
                     OCC5 = OCC4 + S4*S4, OCCW = OCC5 + S5*S5;   // 3537
static constexpr int RB2 = (S2*S2+3)/4, RB3 = (S3*S3+3)/4,
                     RB4 = (S4*S4+3)/4, RB5 = (S5*S5+3)/4;
static constexpr int OCCB = RB2+RB3+RB4+RB5;                     // 885

// levels 0-1 dense grids
static constexpr int L0S = 201, L0C = 200, L0W = 4;
static constexpr int L1S = 101, L1C = 100, L1W = 2;
static constexpr int OCC0W_CNT = L0S * L0S * L0W;     // 161604 u64 words
static constexpr int OCC1W_CNT = L1S * L1S * L1W;     // 20402
static constexpr int CB0_CNT = L0C * L0C * L0W;       // 160000 u64
static constexpr int CB1_CNT = L1C * L1C * L1W;       // 20000
static constexpr int OCC01_WORDS = OCC0W_CNT + OCC1W_CNT;   // 182006

// byte gate grids
static constexpr int B2_CNT   = 50 * 50 * 50;         // 125000
static constexpr int B345_CNT = 25 * 25 * 25;         // 15625
static constexpr int CBTASKS  = CB0_CNT + CB1_CNT + B2_CNT + B345_CNT; // 320625
static constexpr int CBK_BLOCKS = 1 + (CBTASKS + 255) / 256;           // 1254

// bm01: wave-ballot layout. bucket B (lvl*BTAB+key):
//   u64 word = ((B>>8)<<2) | (B&3), bit = (B>>2)&63
static constexpr int BM01_WAVES = (int)(2 * BTAB / 256);    // 32768
static constexpr int BM01B = BM01_WAVES / 4;                // 8192 blocks

// d_out scratch layout (all consumed before main kernel writes out)
static constexpr size_t OUT_BM01_OFF  = 4u  * 1024 * 1024;  // 1 MB
static constexpr size_t OUT_OCC25_OFF = 5u  * 1024 * 1024;  // ~28 KB
static constexpr size_t OUT_OCC0_OFF  = 5632u * 1024;       // 1.3 MB
static constexpr size_t OUT_OCC1_OFF  = 7u  * 1024 * 1024;  // ~160 KB

// ws layout (read by main)
static constexpr size_t SORTED_BYTES = (size_t)NPTS * 16;   // 16 MB
static constexpr size_t CB0_OFF  = SORTED_BYTES;
static constexpr size_t CB1_OFF  = CB0_OFF  + 1310720;
static constexpr size_t B2_OFF   = CB1_OFF  + 163840;
static constexpr size_t B345_OFF = B2_OFF   + 131072;
static constexpr size_t BB_OFF   = B345_OFF + 16384;
static constexpr size_t WS_FULL  = BB_OFF + (size_t)NBIN * 4;   // ~17.6 MB

typedef float f4 __attribute__((ext_vector_type(4)));
typedef int   i4 __attribute__((ext_vector_type(4)));
typedef unsigned long long u64;

// ------------- per-point: 6 levels gated (2 u64 + 2 byte loads) -------------
__device__ __forceinline__ void nhv_point_g(
    float qx, float qy, float qz,
    const float* __restrict__ feat, const int* __restrict__ fidx,
    const u64* __restrict__ cbit0, const u64* __restrict__ cbit1,
    const unsigned char* __restrict__ b2, const unsigned char* __restrict__ b345,
    float acc[NF])
{
    // integer cells per level, all from level-0 cell (exact: pow2 scaling)
    const int ix0 = (int)(qx * 4.0f), iy0 = (int)(qy * 4.0f), iz0 = (int)(qz * 4.0f);
    const int ix1 = ix0 >> 1, iy1 = iy0 >> 1, iz1 = iz0 >> 1;
    const int ix2 = ix0 >> 2, iy2 = iy0 >> 2, iz2 = iz0 >> 2;
    const int ix3 = ix0 >> 3, iy3 = iy0 >> 3, iz3 = iz0 >> 3;

    const u64 w0 = cbit0[(size_t)(iz0 * L0C + iy0) * L0W + (ix0 >> 6)];
    const u64 w1 = cbit1[(size_t)(iz1 * L1C + iy1) * L1W + (ix1 >> 6)];
    const unsigned vb2   = b2  [(iz2 * 50 + iy2) * 50 + ix2];
    const unsigned vb345 = b345[(iz3 * 25 + iy3) * 25 + ix3];

    const unsigned vm = (unsigned)((w0 >> (ix0 & 63)) & 1ull)
                      | ((unsigned)((w1 >> (ix1 & 63)) & 1ull) << 1)
                      | ((vb2   & 1u) << 2)
                      | ((vb345 & 7u) << 3);   // bits 3,4,5 = v3,v4,v5

#pragma unroll
    for (int f = 0; f < NF; ++f) acc[f] = 0.0f;

    auto gather = [&](int lvl, unsigned cx, unsigned cy, unsigned cz,
                      float tx, float ty, float tz) {
        const unsigned h = cx * P0 + cy * P1 + cz * P2;
        const int* __restrict__ tab = fidx + (size_t)lvl * BTAB;
        int id[8];
#pragma unroll
        for (int k = 0; k < 8; ++k) {
            unsigned key = h;
            if (k & 4) key += P0;
            if (k & 2) key += P1;
            if (k & 1) key += P2;
            id[k] = tab[key & BMASK];
        }
        const float wxv[2] = {1.0f - tx, tx};
        const float wyv[2] = {1.0f - ty, ty};
        const float wzv[2] = {1.0f - tz, tz};
        const float* __restrict__ fb = feat + (size_t)lvl * (TTAB * NF);
#pragma unroll
        for (int k = 0; k < 8; ++k) {
            const float c = wxv[(k>>2)&1] * wyv[(k>>1)&1] * wzv[k&1];
            const float4* p = (const float4*)(fb + (size_t)id[k] * NF);
            const float4 lo = p[0], hi = p[1];
            acc[0]+=c*lo.x; acc[1]+=c*lo.y; acc[2]+=c*lo.z; acc[3]+=c*lo.w;
            acc[4]+=c*hi.x; acc[5]+=c*hi.y; acc[6]+=c*hi.z; acc[7]+=c*hi.w;
        }
    };

    if (vm & 1u)
        gather(0, (unsigned)ix0, (unsigned)iy0, (unsigned)iz0,
               qx*4.0f - (float)ix0, qy*4.0f - (float)iy0, qz*4.0f - (float)iz0);
    if (vm & 2u)
        gather(1, (unsigned)ix1, (unsigned)iy1, (unsigned)iz1,
               qx*2.0f - (float)ix1, qy*2.0f - (float)iy1, qz*2.0f - (float)iz1);
    if (vm & 4u)
        gather(2, (unsigned)ix2, (unsigned)iy2, (unsigned)iz2,
               qx - (float)ix2, qy - (float)iy2, qz - (float)iz2);
    if (vm & 8u)
        gather(3, (unsigned)ix3, (unsigned)iy3, (unsigned)iz3,
               qx*0.5f - (float)ix3, qy*0.5f - (float)iy3, qz*0.5f - (float)iz3);
    if (vm & 16u) {
        const int ix4 = ix0 >> 4, iy4 = iy0 >> 4, iz4 = iz0 >> 4;
        gather(4, (unsigned)ix4, (unsigned)iy4, (unsigned)iz4,
               qx*0.25f - (float)ix4, qy*0.25f - (float)iy4, qz*0.25f - (float)iz4);
    }
    if (vm & 32u) {
        const int ix5 = ix0 >> 5, iy5 = iy0 >> 5, iz5 = iz0 >> 5;
        gather(5, (unsigned)ix5, (unsigned)iy5, (unsigned)iz5,
               qx*0.125f - (float)ix5, qy*0.125f - (float)iy5, qz*0.125f - (float)iz5);
    }
}

// ---------------- plain per-point (ws-too-small fallback) -------------------
__device__ __forceinline__ void nhv_point(
    float qx, float qy, float qz,
    const float* __restrict__ feat, const int* __restrict__ fidx, float acc[NF])
{
    float fx[6], fy[6], fz[6];
    unsigned h[6];
#pragma unroll
    for (int i = 0; i < 6; ++i) {
        const float inv = 4.0f / (float)(1 << i);
        const float sx = qx*inv, sy = qy*inv, sz = qz*inv;
        const float bx = floorf(sx), by = floorf(sy), bz = floorf(sz);
        fx[i] = sx-bx; fy[i] = sy-by; fz[i] = sz-bz;
        h[i] = (unsigned)(int)bx*P0 + (unsigned)(int)by*P1 + (unsigned)(int)bz*P2;
    }
    int id[6][8];
#pragma unroll
    for (int i = 0; i < 6; ++i) {
        const int* __restrict__ tab = fidx + (size_t)i * BTAB;
#pragma unroll
        for (int k = 0; k < 8; ++k) {
            unsigned key = h[i];
            if (k & 4) key += P0;
            if (k & 2) key += P1;
            if (k & 1) key += P2;
            id[i][k] = tab[key & BMASK];
        }
    }
#pragma unroll
    for (int f = 0; f < NF; ++f) acc[f] = 0.0f;
#pragma unroll
    for (int i = 0; i < 6; ++i) {
        int mn = id[i][0];
#pragma unroll
        for (int k = 1; k < 8; ++k) mn = min(mn, id[i][k]);
        if (mn > -1) {
            const float wxv[2] = {1.0f - fx[i], fx[i]};
            const float wyv[2] = {1.0f - fy[i], fy[i]};
            const float wzv[2] = {1.0f - fz[i], fz[i]};
            const float* __restrict__ fb = feat + (size_t)i * (TTAB * NF);
#pragma unroll
            for (int k = 0; k < 8; ++k) {
                const float c = wxv[(k>>2)&1] * wyv[(k>>1)&1] * wzv[k&1];
                const float4* p = (const float4*)(fb + (size_t)id[i][k] * NF);
                const float4 lo = p[0], hi = p[1];
                acc[0]+=c*lo.x; acc[1]+=c*lo.y; acc[2]+=c*lo.z; acc[3]+=c*lo.w;
                acc[4]+=c*hi.x; acc[5]+=c*hi.y; acc[6]+=c*hi.z; acc[7]+=c*hi.w;
            }
        }
    }
}

// ---------------- binning ----------------
__device__ __forceinline__ unsigned expand4(unsigned v) {
    return (v & 1u) | ((v & 2u) << 2) | ((v & 4u) << 4) | ((v & 8u) << 6);
}
__device__ __forceinline__ unsigned bin_of(float x, float y, float z) {
    unsigned bx = min(15u, (unsigned)(int)(x * 0.32f));
    unsigned by = min(15u, (unsigned)(int)(y * 0.32f));
    unsigned bz = min(15u, (unsigned)(int)(z * 0.32f));
    return expand4(bx) | (expand4(by) << 1) | (expand4(bz) << 2);
}

// --- pre_k: occ2-5 grids || bm01 build (coalesced ballot) || histogram ------
__global__ __launch_bounds__(256) void pre_k(const int* __restrict__ fidx,
                                             u64* __restrict__ occ25,
                                             u64* __restrict__ bm01,
                                             const float* __restrict__ qp,
                                             unsigned* __restrict__ hist) {
    __shared__ unsigned lh[NBIN];
    const int t = threadIdx.x, b = blockIdx.x;
    if (b < OCCB) {
        int lvl, S, occoff, bb = b;
        if (bb < RB2)              { lvl = 2; S = S2; occoff = OCC2; }
        else if ((bb -= RB2) < RB3){ lvl = 3; S = S3; occoff = OCC3; }
        else if ((bb -= RB3) < RB4){ lvl = 4; S = S4; occoff = OCC4; }
        else        { bb -= RB4;     lvl = 5; S = S5; occoff = OCC5; }
        const int row  = bb * 4 + (t >> 6);
        const int lane = t & 63;
        if (row < S * S) {
            const int y = row % S, z = row / S;
            bool v = false;
            if (lane < S) {
                const unsigned key = ((unsigned)lane*P0 + (unsigned)y*P1
                                    + (unsigned)z*P2) & BMASK;
                v = fidx[(size_t)lvl * BTAB + key] >= 0;
            }
            const u64 m = __ballot(v);
            if (lane == 0) occ25[occoff + row] = m;
        }
    } else if (b < OCCB + BM01B) {
        const int tid  = (b - OCCB) * 256 + t;
        const int w    = tid >> 6;
        const int lane = tid & 63;
        const i4 v = __builtin_nontemporal_load(
                        (const i4*)(fidx + (size_t)w * 256) + lane);
        const u64 m0 = __ballot(v.x >= 0);
        const u64 m1 = __ballot(v.y >= 0);
        const u64 m2 = __ballot(v.z >= 0);
        const u64 m3 = __ballot(v.w >= 0);
        if (lane == 0) {
            u64* d = bm01 + ((size_t)w << 2);
            d[0] = m0; d[1] = m1; d[2] = m2; d[3] = m3;
        }
    } else {
        const int bh = b - OCCB - BM01B;
        for (int i = t; i < NBIN; i += 256) lh[i] = 0u;
        __syncthreads();
        const int base = bh * PPB;
#pragma unroll
        for (int i = 0; i < ITER; ++i) {
            const int p = base + i * 256 + t;
            const float x = __builtin_nontemporal_load(qp + 3*p);
            const float y = __builtin_nontemporal_load(qp + 3*p + 1);
            const float z = __builtin_nontemporal_load(qp + 3*p + 2);
            atomicAdd(&lh[bin_of(x, y, z)], 1u);
        }
        __syncthreads();
        for (int i = t; i < NBIN; i += 256)
            __builtin_nontemporal_store(lh[i], hist + (size_t)bh * NBIN + i);
    }
}

// --- os_k: colscan (blocks 0..15) || occ01 from L2-resident bm01 ------------
__global__ __launch_bounds__(256) void os_k(unsigned* __restrict__ hist,
                                            unsigned* __restrict__ binbase,
                                            const u64* __restrict__ bm01,
                                            u64* __restrict__ occ0,
                                            u64* __restrict__ occ1) {
    const int t = threadIdx.x, b = blockIdx.x;
    if (b < 16) {
        const int bin = b * 256 + t;
        unsigned run = 0;
        for (int blk = 0; blk < SB; ++blk) {
            const unsigned v = hist[(size_t)blk * NBIN + bin];
            hist[(size_t)blk * NBIN + bin] = run;
            run += v;
        }
        binbase[bin] = run;
        return;
    }
    const int lane    = t & 63;
    const int wid     = ((b - 16) * 256 + t) >> 6;
    const int nwaves  = ((int)gridDim.x - 16) * 4;
    const int ngroups = (OCC01_WORDS + 3) / 4;
    for (int g = wid; g < ngroups; g += nwaves) {
        bool vv[4];
        bool ok[4];
#pragma unroll
        for (int k = 0; k < 4; ++k) {
            const int w = g * 4 + k;
            ok[k] = (w < OCC01_WORDS);
            bool v = false;
            if (ok[k]) {
                int S, row, wblk, lvl;
                if (w < OCC0W_CNT) { lvl = 0; S = L0S; row = w >> 2; wblk = w & 3; }
                else { lvl = 1; S = L1S; const int w1 = w - OCC0W_CNT; row = w1 >> 1; wblk = w1 & 1; }
                const int z = row / S, y = row % S;
                const int x = wblk * 64 + lane;
                if (x < S) {
                    const unsigned key = ((unsigned)x*P0 + (unsigned)y*P1
                                        + (unsigned)z*P2) & BMASK;
                    const unsigned B = (unsigned)lvl * BTAB + key;
                    const u64 word = bm01[((size_t)(B >> 8) << 2) | (B & 3u)];
                    v = (word >> ((B >> 2) & 63u)) & 1ull;
                }
            }
            vv[k] = v;
        }
#pragma unroll
        for (int k = 0; k < 4; ++k) {
            const u64 m = __ballot(vv[k]);
            const int w = g * 4 + k;
            if (ok[k] && lane == 0) {
                if (w < OCC0W_CNT) occ0[w] = m;
                else               occ1[w - OCC0W_CNT] = m;
            }
        }
    }
}

// --- cb_k: binscan (block 0) || cbit0 || cbit1 || b2 || b345 derives --------
__global__ __launch_bounds__(256) void cb_k(unsigned* __restrict__ binbase,
                                            const u64* __restrict__ occ25,
                                            const u64* __restrict__ occ0,
                                            const u64* __restrict__ occ1,
                                            u64* __restrict__ cbit0,
                                            u64* __restrict__ cbit1,
                                            unsigned char* __restrict__ b2,
                                            unsigned char* __restrict__ b345) {
    const int t = threadIdx.x, b = blockIdx.x;
    if (b == 0) {   // exclusive scan of 4096 bin totals
        __shared__ unsigned tot[256];
        unsigned v[16];
        unsigned s = 0;
#pragma unroll
        for (int i = 0; i < 16; ++i) { v[i] = s; s += binbase[t * 16 + i]; }
        tot[t] = s;
        __syncthreads();
        for (int d = 1; d < 256; d <<= 1) {
            const unsigned x = (t >= d) ? tot[t - d] : 0u;
            __syncthreads();
            tot[t] += x;
            __syncthreads();
        }
        const unsigned cbv = tot[t] - s;
#pragma unroll
        for (int i = 0; i < 16; ++i) binbase[t * 16 + i] = cbv + v[i];
        return;
    }
    const int c = (b - 1) * 256 + t;
    if (c < CB0_CNT) {
        const int w = c & 3, crow = c >> 2;
        const int cy = crow % L0C, cz = crow / L0C;
        u64 res = ~0ull;
#pragma unroll
        for (int dy = 0; dy < 2; ++dy)
#pragma unroll
            for (int dz = 0; dz < 2; ++dz) {
                const u64* r = occ0 + ((size_t)((cz + dz) * L0S + (cy + dy)) << 2);
                const u64 a = r[w];
                const u64 n = (w < 3) ? r[w + 1] : 0ull;
                res &= a & ((a >> 1) | (n << 63));
            }
        cbit0[c] = res;
    } else if (c < CB0_CNT + CB1_CNT) {
        const int c1 = c - CB0_CNT;
        const int w = c1 & 1, crow = c1 >> 1;
        const int cy = crow % L1C, cz = crow / L1C;
        u64 res = ~0ull;
#pragma unroll
        for (int dy = 0; dy < 2; ++dy)
#pragma unroll
            for (int dz = 0; dz < 2; ++dz) {
                const u64* r = occ1 + ((size_t)((cz + dz) * L1S + (cy + dy)) << 1);
                const u64 a = r[w];
                const u64 n = (w < 1) ? r[w + 1] : 0ull;
                res &= a & ((a >> 1) | (n << 63));
            }
        cbit1[c1] = res;
    } else if (c < CB0_CNT + CB1_CNT + B2_CNT) {
        const int l = c - CB0_CNT - CB1_CNT;
        const int ix = l % 50, iy = (l / 50) % 50, iz = l / 2500;
        u64 m = ~0ull;
#pragma unroll
        for (int dz = 0; dz < 2; ++dz)
#pragma unroll
            for (int dy = 0; dy < 2; ++dy) {
                const u64 r = occ25[OCC2 + (iz + dz) * S2 + (iy + dy)];
                m &= r & (r >> 1);
            }
        b2[l] = (unsigned char)((m >> ix) & 1ull);
    } else {
        const int l = c - CB0_CNT - CB1_CNT - B2_CNT;
        if (l >= B345_CNT) return;
        const int ix = l % 25, iy = (l / 25) % 25, iz = l / 625;
        u64 m3 = ~0ull, m4 = ~0ull, m5 = ~0ull;
#pragma unroll
        for (int dz = 0; dz < 2; ++dz)
#pragma unroll
            for (int dy = 0; dy < 2; ++dy) {
                const u64 r3 = occ25[OCC3 + (iz + dz) * S3 + (iy + dy)];
                const u64 r4 = occ25[OCC4 + ((iz >> 1) + dz) * S4 + ((iy >> 1) + dy)];
                const u64 r5 = occ25[OCC5 + ((iz >> 2) + dz) * S5 + ((iy >> 2) + dy)];
                m3 &= r3 & (r3 >> 1);
                m4 &= r4 & (r4 >> 1);
                m5 &= r5 & (r5 >> 1);
            }
        const unsigned v3 = (unsigned)((m3 >> ix) & 1ull);
        const unsigned v4 = (unsigned)((m4 >> (ix >> 1)) & 1ull);
        const unsigned v5 = (unsigned)((m5 >> (ix >> 2)) & 1ull);
        b345[l] = (unsigned char)(v3 | (v4 << 1) | (v5 << 2));
    }
}

// ---------------- scatter ----------------
__global__ __launch_bounds__(256) void scatter_k(const float* __restrict__ qp,
                                                 const unsigned* __restrict__ hist,
                                                 const unsigned* __restrict__ binbase,
                                                 float4* __restrict__ sorted) {
    __shared__ unsigned cur[NBIN];
    const int b = blockIdx.x, t = threadIdx.x;
    for (int i = t; i < NBIN; i += 256)
        cur[i] = binbase[i] + hist[(size_t)b * NBIN + i];
    __syncthreads();
    const int base = b * PPB;
#pragma unroll
    for (int i = 0; i < ITER; ++i) {
        const int p = base + i * 256 + t;
        const float x = __builtin_nontemporal_load(qp + 3*p);
        const float y = __builtin_nontemporal_load(qp + 3*p + 1);
        const float z = __builtin_nontemporal_load(qp + 3*p + 2);
        const unsigned slot = atomicAdd(&cur[bin_of(x, y, z)], 1u);
        const f4 v = {x, y, z, __uint_as_float((unsigned)p)};
        __builtin_nontemporal_store(v, (f4*)sorted + slot);
    }
}

// ----- main: block = bin; LDS sub-sort (6-bit sub-Morton) + gather ----------
__global__ __launch_bounds__(256) void nhv_main_k(
    const float4* __restrict__ sorted, const unsigned* __restrict__ binbase,
    const float* __restrict__ feat, const int* __restrict__ fidx,
    const u64* __restrict__ cbit0, const u64* __restrict__ cbit1,
    const unsigned char* __restrict__ b2, const unsigned char* __restrict__ b345,
    float* __restrict__ out)
{
    __shared__ float4         pts[BCAP];
    __shared__ unsigned char  sk[BCAP];
    __shared__ unsigned short ord[BCAP];
    __shared__ unsigned       cnt[64];

    const int bid = blockIdx.x;
    const int bin = (bid & 7) * (NBIN >> 3) + (bid >> 3);   // XCD spatial slabs
    const int t   = threadIdx.x;
    const unsigned start = binbase[bin];
    const unsigned end   = (bin < NBIN - 1) ? binbase[bin + 1] : (unsigned)NPTS;
    const int n = (int)(end - start);

    if (n <= BCAP) {
        if (t < 64) cnt[t] = 0u;
        __syncthreads();
#pragma unroll
        for (int r = 0; r < BCAP / 256; ++r) {
            const int i = r * 256 + t;
            if (i < n) {
                const f4 pv = __builtin_nontemporal_load((const f4*)sorted + (start + i));
                pts[i] = make_float4(pv.x, pv.y, pv.z, pv.w);
                const unsigned ux = (unsigned)(int)(pv.x * 1.28f) & 3u;
                const unsigned uy = (unsigned)(int)(pv.y * 1.28f) & 3u;
                const unsigned uz = (unsigned)(int)(pv.z * 1.28f) & 3u;
                const unsigned s = (ux & 1u) | ((uy & 1u) << 1) | ((uz & 1u) << 2)
                                 | ((ux >> 1) << 3) | ((uy >> 1) << 4) | ((uz >> 1) << 5);
                sk[i] = (unsigned char)s;
                atomicAdd(&cnt[s], 1u);
            }
        }
        __syncthreads();
        if (t == 0) {
            unsigned run = 0;
#pragma unroll
            for (int i = 0; i < 64; ++i) { const unsigned v = cnt[i]; cnt[i] = run; run += v; }
        }
        __syncthreads();
#pragma unroll
        for (int r = 0; r < BCAP / 256; ++r) {
            const int i = r * 256 + t;
            if (i < n) ord[atomicAdd(&cnt[sk[i]], 1u)] = (unsigned short)i;
        }
        __syncthreads();
#pragma unroll
        for (int r = 0; r < BCAP / 256; ++r) {
            const int j = r * 256 + t;
            if (j < n) {
                const float4 p = pts[ord[j]];
                float acc[NF];
                nhv_point_g(p.x, p.y, p.z, feat, fidx, cbit0, cbit1, b2, b345, acc);
                const unsigned pn = __float_as_uint(p.w);
                f4* o = (f4*)(out + (size_t)pn * NF);
                f4 lo = {acc[0], acc[1], acc[2], acc[3]};
                f4 hi = {acc[4], acc[5], acc[6], acc[7]};
                __builtin_nontemporal_store(lo, o);
                __builtin_nontemporal_store(hi, o + 1);
            }
        }
    } else {  // oversize bin (rare): process unsorted, still correct
        for (int j = t; j < n; j += 256) {
            const f4 pv = __builtin_nontemporal_load((const f4*)sorted + (start + j));
            float acc[NF];
            nhv_point_g(pv.x, pv.y, pv.z, feat, fidx, cbit0, cbit1, b2, b345, acc);
            const unsigned pn = __float_as_uint(pv.w);
            f4* o = (f4*)(out + (size_t)pn * NF);
            f4 lo = {acc[0], acc[1], acc[2], acc[3]};
            f4 hi = {acc[4], acc[5], acc[6], acc[7]};
            __builtin_nontemporal_store(lo, o);
            __builtin_nontemporal_store(hi, o + 1);
        }
    }
}

// ---------------- fallback ----------------
__global__ __launch_bounds__(256) void nhv_direct_k(
    const float* __restrict__ qp, const float* __restrict__ feat,
    const int* __restrict__ fidx, float* __restrict__ out)
{
    const int n = blockIdx.x * 256 + threadIdx.x;
    if (n >= NPTS) return;
    float acc[NF];
    nhv_point(qp[3*n], qp[3*n+1], qp[3*n+2], feat, fidx, acc);
    float4* o = (float4*)(out + (size_t)n * NF);
    o[0] = make_float4(acc[0], acc[1], acc[2], acc[3]);
    o[1] = make_float4(acc[4], acc[5], acc[6], acc[7]);
}

extern "C" void kernel_launch(void* const* d_in, const int* in_sizes, int n_in,
                              void* d_out, int out_size, void* d_ws, size_t ws_size,
                              hipStream_t stream) {
    const float* qp   = (const float*)d_in[0];
    const float* feat = (const float*)d_in[1];
    const int*   fidx = (const int*)d_in[2];
    float*       out  = (float*)d_out;

    if (ws_size >= WS_FULL) {
        // ws (read by main): sorted | cbit0 | cbit1 | b2 | b345 | binbase
        float4*        sorted  = (float4*)d_ws;
        u64*           cbit0   = (u64*)((char*)d_ws + CB0_OFF);
        u64*           cbit1   = (u64*)((char*)d_ws + CB1_OFF);
        unsigned char* b2      = (unsigned char*)((char*)d_ws + B2_OFF);
        unsigned char* b345    = (unsigned char*)((char*)d_ws + B345_OFF);
        unsigned*      binbase = (unsigned*)((char*)d_ws + BB_OFF);
        // d_out scratch (all consumed before main overwrites out):
        unsigned*      hist  = (unsigned*)d_out;
        u64*           bm01  = (u64*)((char*)d_out + OUT_BM01_OFF);
        u64*           occ25 = (u64*)((char*)d_out + OUT_OCC25_OFF);
        u64*           occ0  = (u64*)((char*)d_out + OUT_OCC0_OFF);
        u64*           occ1  = (u64*)((char*)d_out + OUT_OCC1_OFF);

        pre_k<<<dim3(OCCB + BM01B + SB), dim3(256), 0, stream>>>(fidx, occ25, bm01, qp, hist);
        os_k<<<dim3(16 + 512), dim3(256), 0, stream>>>(hist, binbase, bm01, occ0, occ1);
        cb_k<<<dim3(CBK_BLOCKS), dim3(256), 0, stream>>>(binbase, occ25, occ0, occ1,
                                                         cbit0, cbit1, b2, b345);
        scatter_k<<<dim3(SB), dim3(256), 0, stream>>>(qp, hist, binbase, sorted);
        nhv_main_k<<<dim3(NBIN), dim3(256), 0, stream>>>(sorted, binbase, feat, fidx,
                                                         cbit0, cbit1, b2, b345, out);
    } else {
        nhv_direct_k<<<dim3(NPTS/256), dim3(256), 0, stream>>>(qp, feat, fidx, out);
    }
}

// Round 16
// 200.783 us; speedup vs baseline: 1.5917x; 1.0307x over previous
//
#include <hip/hip_runtime.h>

// NeuralHashVoxel round 16: 4-launch pipeline.
//  pre_k  (hist FIRST || bm01 || occ25, zeroes done_ctr)
//  os_k   (colscan || occ01; last-finisher colscan block runs binscan)
//  cs_k   (scatter blocks first || cbit0/cbit1/b2/b345 derives)
//  main_k (unchanged from r15: per-bin LDS sub-sort + gated gathers)

static constexpr int      NPTS  = 1048576;
static constexpr int      NF    = 8;
static constexpr int      TTAB  = 524288;
static constexpr unsigned BTAB  = 4194304u;          // 2^22 buckets per level
static constexpr unsigned BMASK = BTAB - 1u;
static constexpr unsigned P0 = 73856093u, P1 = 19349669u, P2 = 83492791u;

static constexpr int NBIN = 4096;        // 16^3 Morton bins, cell = 3.125
static constexpr int SB   = 256;
static constexpr int PPB  = NPTS / SB;
static constexpr int ITER = PPB / 256;
static constexpr int BCAP = 512;

// vertex-grid dims for levels 2..5 (scaled coords < 50,25,12.5,6.25)
static constexpr int S2 = 51, S3 = 26, S4 = 14, S5 = 8;
static constexpr int OCC2 = 0, OCC3 = OCC2 + S2*S2, OCC4 = OCC3 + S3*S3,
                     OCC5 = OCC4 + S4*S4, OCCW = OCC5 + S5*S5;   // 3537
static constexpr int RB2 = (S2*S2+3)/4, RB3 = (S3*S3+3)/4,
                     RB4 = (S4*S4+3)/4, RB5 = (S5*S5+3)/4;
static constexpr int OCCB = RB2+RB3+RB4+RB5;                     // 885

// levels 0-1 dense grids
static constexpr int L0S = 201, L0C = 200, L0W = 4;
static constexpr int L1S = 101, L1C = 100, L1W = 2;
static constexpr int OCC0W_CNT = L0S * L0S * L0W;     // 161604 u64 words
static constexpr int OCC1W_CNT = L1S * L1S * L1W;     // 20402
static constexpr int CB0_CNT = L0C * L0C * L0W;       // 160000 u64
static constexpr int CB1_CNT = L1C * L1C * L1W;       // 20000
static constexpr int OCC01_WORDS = OCC0W_CNT + OCC1W_CNT;   // 182006

// byte gate grids
static constexpr int B2_CNT   = 50 * 50 * 50;         // 125000
static constexpr int B345_CNT = 25 * 25 * 25;         // 15625
static constexpr int CBTASKS  = CB0_CNT + CB1_CNT + B2_CNT + B345_CNT; // 320625
static constexpr int CS_BLOCKS = SB + (CBTASKS + 255) / 256;           // 1509

// bm01: wave-ballot layout. bucket B (lvl*BTAB+key):
//   u64 word = ((B>>8)<<2) | (B&3), bit = (B>>2)&63
static constexpr int BM01_WAVES = (int)(2 * BTAB / 256);    // 32768
static constexpr int BM01B = BM01_WAVES / 4;                // 8192 blocks

// d_out scratch layout (all consumed before main kernel writes out)
static constexpr size_t OUT_BM01_OFF  = 4u  * 1024 * 1024;  // 1 MB
static constexpr size_t OUT_OCC25_OFF = 5u  * 1024 * 1024;  // ~28 KB
static constexpr size_t OUT_OCC0_OFF  = 5632u * 1024;       // 1.3 MB
static constexpr size_t OUT_OCC1_OFF  = 7u  * 1024 * 1024;  // ~160 KB

// ws layout (read by main)
static constexpr size_t SORTED_BYTES = (size_t)NPTS * 16;   // 16 MB
static constexpr size_t CB0_OFF  = SORTED_BYTES;
static constexpr size_t CB1_OFF  = CB0_OFF  + 1310720;
static constexpr size_t B2_OFF   = CB1_OFF  + 163840;
static constexpr size_t B345_OFF = B2_OFF   + 131072;
static constexpr size_t BB_OFF   = B345_OFF + 16384;
static constexpr size_t DONE_OFF = BB_OFF + (size_t)NBIN * 4;
static constexpr size_t WS_FULL  = DONE_OFF + 256;

typedef float f4 __attribute__((ext_vector_type(4)));
typedef int   i4 __attribute__((ext_vector_type(4)));
typedef unsigned long long u64;

// ------------- per-point: 6 levels gated (2 u64 + 2 byte loads) -------------
__device__ __forceinline__ void nhv_point_g(
    float qx, float qy, float qz,
    const float* __restrict__ feat, const int* __restrict__ fidx,
    const u64* __restrict__ cbit0, const u64* __restrict__ cbit1,
    const unsigned char* __restrict__ b2, const unsigned char* __restrict__ b345,
    float acc[NF])
{
    const int ix0 = (int)(qx * 4.0f), iy0 = (int)(qy * 4.0f), iz0 = (int)(qz * 4.0f);
    const int ix1 = ix0 >> 1, iy1 = iy0 >> 1, iz1 = iz0 >> 1;
    const int ix2 = ix0 >> 2, iy2 = iy0 >> 2, iz2 = iz0 >> 2;
    const int ix3 = ix0 >> 3, iy3 = iy0 >> 3, iz3 = iz0 >> 3;

    const u64 w0 = cbit0[(size_t)(iz0 * L0C + iy0) * L0W + (ix0 >> 6)];
    const u64 w1 = cbit1[(size_t)(iz1 * L1C + iy1) * L1W + (ix1 >> 6)];
    const unsigned vb2   = b2  [(iz2 * 50 + iy2) * 50 + ix2];
    const unsigned vb345 = b345[(iz3 * 25 + iy3) * 25 + ix3];

    const unsigned vm = (unsigned)((w0 >> (ix0 & 63)) & 1ull)
                      | ((unsigned)((w1 >> (ix1 & 63)) & 1ull) << 1)
                      | ((vb2   & 1u) << 2)
                      | ((vb345 & 7u) << 3);   // bits 3,4,5 = v3,v4,v5

#pragma unroll
    for (int f = 0; f < NF; ++f) acc[f] = 0.0f;

    auto gather = [&](int lvl, unsigned cx, unsigned cy, unsigned cz,
                      float tx, float ty, float tz) {
        const unsigned h = cx * P0 + cy * P1 + cz * P2;
        const int* __restrict__ tab = fidx + (size_t)lvl * BTAB;
        int id[8];
#pragma unroll
        for (int k = 0; k < 8; ++k) {
            unsigned key = h;
            if (k & 4) key += P0;
            if (k & 2) key += P1;
            if (k & 1) key += P2;
            id[k] = tab[key & BMASK];
        }
        const float wxv[2] = {1.0f - tx, tx};
        const float wyv[2] = {1.0f - ty, ty};
        const float wzv[2] = {1.0f - tz, tz};
        const float* __restrict__ fb = feat + (size_t)lvl * (TTAB * NF);
#pragma unroll
        for (int k = 0; k < 8; ++k) {
            const float c = wxv[(k>>2)&1] * wyv[(k>>1)&1] * wzv[k&1];
            const float4* p = (const float4*)(fb + (size_t)id[k] * NF);
            const float4 lo = p[0], hi = p[1];
            acc[0]+=c*lo.x; acc[1]+=c*lo.y; acc[2]+=c*lo.z; acc[3]+=c*lo.w;
            acc[4]+=c*hi.x; acc[5]+=c*hi.y; acc[6]+=c*hi.z; acc[7]+=c*hi.w;
        }
    };

    if (vm & 1u)
        gather(0, (unsigned)ix0, (unsigned)iy0, (unsigned)iz0,
               qx*4.0f - (float)ix0, qy*4.0f - (float)iy0, qz*4.0f - (float)iz0);
    if (vm & 2u)
        gather(1, (unsigned)ix1, (unsigned)iy1, (unsigned)iz1,
               qx*2.0f - (float)ix1, qy*2.0f - (float)iy1, qz*2.0f - (float)iz1);
    if (vm & 4u)
        gather(2, (unsigned)ix2, (unsigned)iy2, (unsigned)iz2,
               qx - (float)ix2, qy - (float)iy2, qz - (float)iz2);
    if (vm & 8u)
        gather(3, (unsigned)ix3, (unsigned)iy3, (unsigned)iz3,
               qx*0.5f - (float)ix3, qy*0.5f - (float)iy3, qz*0.5f - (float)iz3);
    if (vm & 16u) {
        const int ix4 = ix0 >> 4, iy4 = iy0 >> 4, iz4 = iz0 >> 4;
        gather(4, (unsigned)ix4, (unsigned)iy4, (unsigned)iz4,
               qx*0.25f - (float)ix4, qy*0.25f - (float)iy4, qz*0.25f - (float)iz4);
    }
    if (vm & 32u) {
        const int ix5 = ix0 >> 5, iy5 = iy0 >> 5, iz5 = iz0 >> 5;
        gather(5, (unsigned)ix5, (unsigned)iy5, (unsigned)iz5,
               qx*0.125f - (float)ix5, qy*0.125f - (float)iy5, qz*0.125f - (float)iz5);
    }
}

// ---------------- plain per-point (ws-too-small fallback) -------------------
__device__ __forceinline__ void nhv_point(
    float qx, float qy, float qz,
    const float* __restrict__ feat, const int* __restrict__ fidx, float acc[NF])
{
    float fx[6], fy[6], fz[6];
    unsigned h[6];
#pragma unroll
    for (int i = 0; i < 6; ++i) {
        const float inv = 4.0f / (float)(1 << i);
        const float sx = qx*inv, sy = qy*inv, sz = qz*inv;
        const float bx = floorf(sx), by = floorf(sy), bz = floorf(sz);
        fx[i] = sx-bx; fy[i] = sy-by; fz[i] = sz-bz;
        h[i] = (unsigned)(int)bx*P0 + (unsigned)(int)by*P1 + (unsigned)(int)bz*P2;
    }
    int id[6][8];
#pragma unroll
    for (int i = 0; i < 6; ++i) {
        const int* __restrict__ tab = fidx + (size_t)i * BTAB;
#pragma unroll
        for (int k = 0; k < 8; ++k) {
            unsigned key = h[i];
            if (k & 4) key += P0;
            if (k & 2) key += P1;
            if (k & 1) key += P2;
            id[i][k] = tab[key & BMASK];
        }
    }
#pragma unroll
    for (int f = 0; f < NF; ++f) acc[f] = 0.0f;
#pragma unroll
    for (int i = 0; i < 6; ++i) {
        int mn = id[i][0];
#pragma unroll
        for (int k = 1; k < 8; ++k) mn = min(mn, id[i][k]);
        if (mn > -1) {
            const float wxv[2] = {1.0f - fx[i], fx[i]};
            const float wyv[2] = {1.0f - fy[i], fy[i]};
            const float wzv[2] = {1.0f - fz[i], fz[i]};
            const float* __restrict__ fb = feat + (size_t)i * (TTAB * NF);
#pragma unroll
            for (int k = 0; k < 8; ++k) {
                const float c = wxv[(k>>2)&1] * wyv[(k>>1)&1] * wzv[k&1];
                const float4* p = (const float4*)(fb + (size_t)id[i][k] * NF);
                const float4 lo = p[0], hi = p[1];
                acc[0]+=c*lo.x; acc[1]+=c*lo.y; acc[2]+=c*lo.z; acc[3]+=c*lo.w;
                acc[4]+=c*hi.x; acc[5]+=c*hi.y; acc[6]+=c*hi.z; acc[7]+=c*hi.w;
            }
        }
    }
}

// ---------------- binning ----------------
__device__ __forceinline__ unsigned expand4(unsigned v) {
    return (v & 1u) | ((v & 2u) << 2) | ((v & 4u) << 4) | ((v & 8u) << 6);
}
__device__ __forceinline__ unsigned bin_of(float x, float y, float z) {
    unsigned bx = min(15u, (unsigned)(int)(x * 0.32f));
    unsigned by = min(15u, (unsigned)(int)(y * 0.32f));
    unsigned bz = min(15u, (unsigned)(int)(z * 0.32f));
    return expand4(bx) | (expand4(by) << 1) | (expand4(bz) << 2);
}

// --- pre_k: histogram FIRST || bm01 build || occ2-5 grids; zeroes done_ctr --
__global__ __launch_bounds__(256) void pre_k(const int* __restrict__ fidx,
                                             u64* __restrict__ occ25,
                                             u64* __restrict__ bm01,
                                             const float* __restrict__ qp,
                                             unsigned* __restrict__ hist,
                                             unsigned* __restrict__ done_ctr) {
    __shared__ unsigned lh[NBIN];
    const int t = threadIdx.x, b = blockIdx.x;
    if (b == 0 && t == 0) *done_ctr = 0u;   // reset for os_k (every call)
    if (b < SB) {
        // histogram (longest-running blocks -> start first)
        for (int i = t; i < NBIN; i += 256) lh[i] = 0u;
        __syncthreads();
        const int base = b * PPB;
#pragma unroll
        for (int i = 0; i < ITER; ++i) {
            const int p = base + i * 256 + t;
            atomicAdd(&lh[bin_of(qp[3*p], qp[3*p+1], qp[3*p+2])], 1u);
        }
        __syncthreads();
        for (int i = t; i < NBIN; i += 256)
            __builtin_nontemporal_store(lh[i], hist + (size_t)b * NBIN + i);
    } else if (b < SB + BM01B) {
        // bm01: wave w covers buckets [w*256,(w+1)*256); lane l: buckets 4l+k
        const int tid  = (b - SB) * 256 + t;
        const int w    = tid >> 6;
        const int lane = tid & 63;
        const i4 v = __builtin_nontemporal_load(
                        (const i4*)(fidx + (size_t)w * 256) + lane);
        const u64 m0 = __ballot(v.x >= 0);
        const u64 m1 = __ballot(v.y >= 0);
        const u64 m2 = __ballot(v.z >= 0);
        const u64 m3 = __ballot(v.w >= 0);
        if (lane == 0) {
            u64* d = bm01 + ((size_t)w << 2);
            d[0] = m0; d[1] = m1; d[2] = m2; d[3] = m3;
        }
    } else {
        int lvl, S, occoff, bb = b - SB - BM01B;
        if (bb < RB2)              { lvl = 2; S = S2; occoff = OCC2; }
        else if ((bb -= RB2) < RB3){ lvl = 3; S = S3; occoff = OCC3; }
        else if ((bb -= RB3) < RB4){ lvl = 4; S = S4; occoff = OCC4; }
        else        { bb -= RB4;     lvl = 5; S = S5; occoff = OCC5; }
        const int row  = bb * 4 + (t >> 6);
        const int lane = t & 63;
        if (row < S * S) {
            const int y = row % S, z = row / S;
            bool v = false;
            if (lane < S) {
                const unsigned key = ((unsigned)lane*P0 + (unsigned)y*P1
                                    + (unsigned)z*P2) & BMASK;
                v = fidx[(size_t)lvl * BTAB + key] >= 0;
            }
            const u64 m = __ballot(v);
            if (lane == 0) occ25[occoff + row] = m;
        }
    }
}

// --- os_k: colscan (0..15, last-finisher runs binscan) || occ01 probes ------
__global__ __launch_bounds__(256) void os_k(unsigned* __restrict__ hist,
                                            unsigned* __restrict__ binbase,
                                            const u64* __restrict__ bm01,
                                            u64* __restrict__ occ0,
                                            u64* __restrict__ occ1,
                                            unsigned* __restrict__ done_ctr) {
    __shared__ unsigned tot[256];
    __shared__ int is_last;
    const int t = threadIdx.x, b = blockIdx.x;
    if (b < 16) {
        const int bin = b * 256 + t;
        unsigned run = 0;
        for (int blk = 0; blk < SB; ++blk) {
            const unsigned v = hist[(size_t)blk * NBIN + bin];
            hist[(size_t)blk * NBIN + bin] = run;
            run += v;
        }
        binbase[bin] = run;
        __threadfence();                      // publish binbase (release)
        __syncthreads();
        if (t == 0) is_last = (atomicAdd(done_ctr, 1u) == 15u);
        __syncthreads();
        if (is_last) {                        // all 16 colscans visible
            __threadfence();                  // acquire
            unsigned v[16];
            unsigned s = 0;
#pragma unroll
            for (int i = 0; i < 16; ++i) { v[i] = s; s += binbase[t * 16 + i]; }
            tot[t] = s;
            __syncthreads();
            for (int d = 1; d < 256; d <<= 1) {
                const unsigned x = (t >= d) ? tot[t - d] : 0u;
                __syncthreads();
                tot[t] += x;
                __syncthreads();
            }
            const unsigned cbv = tot[t] - s;
#pragma unroll
            for (int i = 0; i < 16; ++i) binbase[t * 16 + i] = cbv + v[i];
        }
        return;
    }
    const int lane    = t & 63;
    const int wid     = ((b - 16) * 256 + t) >> 6;
    const int nwaves  = ((int)gridDim.x - 16) * 4;
    const int ngroups = (OCC01_WORDS + 3) / 4;
    for (int g = wid; g < ngroups; g += nwaves) {
        bool vv[4];
        bool ok[4];
#pragma unroll
        for (int k = 0; k < 4; ++k) {
            const int w = g * 4 + k;
            ok[k] = (w < OCC01_WORDS);
            bool v = false;
            if (ok[k]) {
                int S, row, wblk, lvl;
                if (w < OCC0W_CNT) { lvl = 0; S = L0S; row = w >> 2; wblk = w & 3; }
                else { lvl = 1; S = L1S; const int w1 = w - OCC0W_CNT; row = w1 >> 1; wblk = w1 & 1; }
                const int z = row / S, y = row % S;
                const int x = wblk * 64 + lane;
                if (x < S) {
                    const unsigned key = ((unsigned)x*P0 + (unsigned)y*P1
                                        + (unsigned)z*P2) & BMASK;
                    const unsigned B = (unsigned)lvl * BTAB + key;
                    const u64 word = bm01[((size_t)(B >> 8) << 2) | (B & 3u)];
                    v = (word >> ((B >> 2) & 63u)) & 1ull;
                }
            }
            vv[k] = v;
        }
#pragma unroll
        for (int k = 0; k < 4; ++k) {
            const u64 m = __ballot(vv[k]);
            const int w = g * 4 + k;
            if (ok[k] && lane == 0) {
                if (w < OCC0W_CNT) occ0[w] = m;
                else               occ1[w - OCC0W_CNT] = m;
            }
        }
    }
}

// --- cs_k: scatter (blocks 0..SB-1, heavy, first) || gate derives -----------
__global__ __launch_bounds__(256) void cs_k(const float* __restrict__ qp,
                                            const unsigned* __restrict__ hist,
                                            const unsigned* __restrict__ binbase,
                                            float4* __restrict__ sorted,
                                            const u64* __restrict__ occ25,
                                            const u64* __restrict__ occ0,
                                            const u64* __restrict__ occ1,
                                            u64* __restrict__ cbit0,
                                            u64* __restrict__ cbit1,
                                            unsigned char* __restrict__ b2,
                                            unsigned char* __restrict__ b345) {
    __shared__ unsigned cur[NBIN];
    const int t = threadIdx.x, b = blockIdx.x;
    if (b < SB) {
        for (int i = t; i < NBIN; i += 256)
            cur[i] = binbase[i] + hist[(size_t)b * NBIN + i];
        __syncthreads();
        const int base = b * PPB;
#pragma unroll
        for (int i = 0; i < ITER; ++i) {
            const int p = base + i * 256 + t;
            const float x = __builtin_nontemporal_load(qp + 3*p);
            const float y = __builtin_nontemporal_load(qp + 3*p + 1);
            const float z = __builtin_nontemporal_load(qp + 3*p + 2);
            const unsigned slot = atomicAdd(&cur[bin_of(x, y, z)], 1u);
            const f4 v = {x, y, z, __uint_as_float((unsigned)p)};
            __builtin_nontemporal_store(v, (f4*)sorted + slot);
        }
        return;
    }
    const int c = (b - SB) * 256 + t;
    if (c < CB0_CNT) {
        const int w = c & 3, crow = c >> 2;
        const int cy = crow % L0C, cz = crow / L0C;
        u64 res = ~0ull;
#pragma unroll
        for (int dy = 0; dy < 2; ++dy)
#pragma unroll
            for (int dz = 0; dz < 2; ++dz) {
                const u64* r = occ0 + ((size_t)((cz + dz) * L0S + (cy + dy)) << 2);
                const u64 a = r[w];
                const u64 n = (w < 3) ? r[w + 1] : 0ull;
                res &= a & ((a >> 1) | (n << 63));
            }
        cbit0[c] = res;
    } else if (c < CB0_CNT + CB1_CNT) {
        const int c1 = c - CB0_CNT;
        const int w = c1 & 1, crow = c1 >> 1;
        const int cy = crow % L1C, cz = crow / L1C;
        u64 res = ~0ull;
#pragma unroll
        for (int dy = 0; dy < 2; ++dy)
#pragma unroll
            for (int dz = 0; dz < 2; ++dz) {
                const u64* r = occ1 + ((size_t)((cz + dz) * L1S + (cy + dy)) << 1);
                const u64 a = r[w];
                const u64 n = (w < 1) ? r[w + 1] : 0ull;
                res &= a & ((a >> 1) | (n << 63));
            }
        cbit1[c1] = res;
    } else if (c < CB0_CNT + CB1_CNT + B2_CNT) {
        const int l = c - CB0_CNT - CB1_CNT;
        const int ix = l % 50, iy = (l / 50) % 50, iz = l / 2500;
        u64 m = ~0ull;
#pragma unroll
        for (int dz = 0; dz < 2; ++dz)
#pragma unroll
            for (int dy = 0; dy < 2; ++dy) {
                const u64 r = occ25[OCC2 + (iz + dz) * S2 + (iy + dy)];
                m &= r & (r >> 1);
            }
        b2[l] = (unsigned char)((m >> ix) & 1ull);
    } else {
        const int l = c - CB0_CNT - CB1_CNT - B2_CNT;
        if (l >= B345_CNT) return;
        const int ix = l % 25, iy = (l / 25) % 25, iz = l / 625;
        u64 m3 = ~0ull, m4 = ~0ull, m5 = ~0ull;
#pragma unroll
        for (int dz = 0; dz < 2; ++dz)
#pragma unroll
            for (int dy = 0; dy < 2; ++dy) {
                const u64 r3 = occ25[OCC3 + (iz + dz) * S3 + (iy + dy)];
                const u64 r4 = occ25[OCC4 + ((iz >> 1) + dz) * S4 + ((iy >> 1) + dy)];
                const u64 r5 = occ25[OCC5 + ((iz >> 2) + dz) * S5 + ((iy >> 2) + dy)];
                m3 &= r3 & (r3 >> 1);
                m4 &= r4 & (r4 >> 1);
                m5 &= r5 & (r5 >> 1);
            }
        const unsigned v3 = (unsigned)((m3 >> ix) & 1ull);
        const unsigned v4 = (unsigned)((m4 >> (ix >> 1)) & 1ull);
        const unsigned v5 = (unsigned)((m5 >> (ix >> 2)) & 1ull);
        b345[l] = (unsigned char)(v3 | (v4 << 1) | (v5 << 2));
    }
}

// ----- main: block = bin; LDS sub-sort (6-bit sub-Morton) + gather ----------
__global__ __launch_bounds__(256) void nhv_main_k(
    const float4* __restrict__ sorted, const unsigned* __restrict__ binbase,
    const float* __restrict__ feat, const int* __restrict__ fidx,
    const u64* __restrict__ cbit0, const u64* __restrict__ cbit1,
    const unsigned char* __restrict__ b2, const unsigned char* __restrict__ b345,
    float* __restrict__ out)
{
    __shared__ float4         pts[BCAP];
    __shared__ unsigned char  sk[BCAP];
    __shared__ unsigned short ord[BCAP];
    __shared__ unsigned       cnt[64];

    const int bid = blockIdx.x;
    const int bin = (bid & 7) * (NBIN >> 3) + (bid >> 3);   // XCD spatial slabs
    const int t   = threadIdx.x;
    const unsigned start = binbase[bin];
    const unsigned end   = (bin < NBIN - 1) ? binbase[bin + 1] : (unsigned)NPTS;
    const int n = (int)(end - start);

    if (n <= BCAP) {
        if (t < 64) cnt[t] = 0u;
        __syncthreads();
#pragma unroll
        for (int r = 0; r < BCAP / 256; ++r) {
            const int i = r * 256 + t;
            if (i < n) {
                const f4 pv = __builtin_nontemporal_load((const f4*)sorted + (start + i));
                pts[i] = make_float4(pv.x, pv.y, pv.z, pv.w);
                const unsigned ux = (unsigned)(int)(pv.x * 1.28f) & 3u;
                const unsigned uy = (unsigned)(int)(pv.y * 1.28f) & 3u;
                const unsigned uz = (unsigned)(int)(pv.z * 1.28f) & 3u;
                const unsigned s = (ux & 1u) | ((uy & 1u) << 1) | ((uz & 1u) << 2)
                                 | ((ux >> 1) << 3) | ((uy >> 1) << 4) | ((uz >> 1) << 5);
                sk[i] = (unsigned char)s;
                atomicAdd(&cnt[s], 1u);
            }
        }
        __syncthreads();
        if (t == 0) {
            unsigned run = 0;
#pragma unroll
            for (int i = 0; i < 64; ++i) { const unsigned v = cnt[i]; cnt[i] = run; run += v; }
        }
        __syncthreads();
#pragma unroll
        for (int r = 0; r < BCAP / 256; ++r) {
            const int i = r * 256 + t;
            if (i < n) ord[atomicAdd(&cnt[sk[i]], 1u)] = (unsigned short)i;
        }
        __syncthreads();
#pragma unroll
        for (int r = 0; r < BCAP / 256; ++r) {
            const int j = r * 256 + t;
            if (j < n) {
                const float4 p = pts[ord[j]];
                float acc[NF];
                nhv_point_g(p.x, p.y, p.z, feat, fidx, cbit0, cbit1, b2, b345, acc);
                const unsigned pn = __float_as_uint(p.w);
                f4* o = (f4*)(out + (size_t)pn * NF);
                f4 lo = {acc[0], acc[1], acc[2], acc[3]};
                f4 hi = {acc[4], acc[5], acc[6], acc[7]};
                __builtin_nontemporal_store(lo, o);
                __builtin_nontemporal_store(hi, o + 1);
            }
        }
    } else {  // oversize bin (rare): process unsorted, still correct
        for (int j = t; j < n; j += 256) {
            const f4 pv = __builtin_nontemporal_load((const f4*)sorted + (start + j));
            float acc[NF];
            nhv_point_g(pv.x, pv.y, pv.z, feat, fidx, cbit0, cbit1, b2, b345, acc);
            const unsigned pn = __float_as_uint(pv.w);
            f4* o = (f4*)(out + (size_t)pn * NF);
            f4 lo = {acc[0], acc[1], acc[2], acc[3]};
            f4 hi = {acc[4], acc[5], acc[6], acc[7]};
            __builtin_nontemporal_store(lo, o);
            __builtin_nontemporal_store(hi, o + 1);
        }
    }
}

// ---------------- fallback ----------------
__global__ __launch_bounds__(256) void nhv_direct_k(
    const float* __restrict__ qp, const float* __restrict__ feat,
    const int* __restrict__ fidx, float* __restrict__ out)
{
    const int n = blockIdx.x * 256 + threadIdx.x;
    if (n >= NPTS) return;
    float acc[NF];
    nhv_point(qp[3*n], qp[3*n+1], qp[3*n+2], feat, fidx, acc);
    float4* o = (float4*)(out + (size_t)n * NF);
    o[0] = make_float4(acc[0], acc[1], acc[2], acc[3]);
    o[1] = make_float4(acc[4], acc[5], acc[6], acc[7]);
}

extern "C" void kernel_launch(void* const* d_in, const int* in_sizes, int n_in,
                              void* d_out, int out_size, void* d_ws, size_t ws_size,
                              hipStream_t stream) {
    const float* qp   = (const float*)d_in[0];
    const float* feat = (const float*)d_in[1];
    const int*   fidx = (const int*)d_in[2];
    float*       out  = (float*)d_out;

    if (ws_size >= WS_FULL) {
        // ws (read by main): sorted | cbit0 | cbit1 | b2 | b345 | binbase | done
        float4*        sorted  = (float4*)d_ws;
        u64*           cbit0   = (u64*)((char*)d_ws + CB0_OFF);
        u64*           cbit1   = (u64*)((char*)d_ws + CB1_OFF);
        unsigned char* b2      = (unsigned char*)((char*)d_ws + B2_OFF);
        unsigned char* b345    = (unsigned char*)((char*)d_ws + B345_OFF);
        unsigned*      binbase = (unsigned*)((char*)d_ws + BB_OFF);
        unsigned*      done    = (unsigned*)((char*)d_ws + DONE_OFF);
        // d_out scratch (all consumed before main overwrites out):
        unsigned*      hist  = (unsigned*)d_out;
        u64*           bm01  = (u64*)((char*)d_out + OUT_BM01_OFF);
        u64*           occ25 = (u64*)((char*)d_out + OUT_OCC25_OFF);
        u64*           occ0  = (u64*)((char*)d_out + OUT_OCC0_OFF);
        u64*           occ1  = (u64*)((char*)d_out + OUT_OCC1_OFF);

        pre_k<<<dim3(SB + BM01B + OCCB), dim3(256), 0, stream>>>(fidx, occ25, bm01,
                                                                 qp, hist, done);
        os_k<<<dim3(16 + 512), dim3(256), 0, stream>>>(hist, binbase, bm01,
                                                       occ0, occ1, done);
        cs_k<<<dim3(CS_BLOCKS), dim3(256), 0, stream>>>(qp, hist, binbase, sorted,
                                                        occ25, occ0, occ1,
                                                        cbit0, cbit1, b2, b345);
        nhv_main_k<<<dim3(NBIN), dim3(256), 0, stream>>>(sorted, binbase, feat, fidx,
                                                         cbit0, cbit1, b2, b345, out);
    } else {
        nhv_direct_k<<<dim3(NPTS/256), dim3(256), 0, stream>>>(qp, feat, fidx, out);
    }
}